// Round 22
// baseline (3759.744 us; speedup 1.0000x reference)
//
#include <hip/hip_runtime.h>
#include <hip/hip_bf16.h>
#include <math.h>

// InstructPerceiverResampler on MI355X (gfx950).
// Round 22 (base = R21, 3670us): co-schedule independent work to kill
// machine-fill tails:
//  (1) gemm_qkvx = q|kv (576 blocks) + kvx (2208 blocks) merged into ONE
//      2784-block dispatch (they are mutually independent; both feed flash).
//      kvx blocks backfill q|kv's 12%-fill straggler phase.
//  (2) convT_wall = convT_qkv + convT_ffo merged (17280 blocks, same bodies).
// Everything else identical to R21 (verified, absmax 0.03125).

typedef __attribute__((ext_vector_type(4))) float f32x4;
typedef __attribute__((ext_vector_type(8))) short bf16x8;
typedef unsigned int u32;

#define DEV __device__ __forceinline__

DEV float bf2f(short s){ union{u32 u; float f;} v; v.u = ((u32)(unsigned short)s) << 16; return v.f; }
DEV short f2bf(float f){
  union{float f; u32 u;} v; v.f = f;
  u32 r = (v.u + 0x7FFFu + ((v.u >> 16) & 1u)) >> 16;
  return (short)r;
}

DEV u32 lds_off(const short* p){
  return (u32)(uintptr_t)(__attribute__((address_space(3))) const short*)p;
}
template<int OFF>
DEV bf16x8 dsro(u32 addr){
  bf16x8 r;
  asm volatile("ds_read_b128 %0, %1 offset:%2" : "=v"(r) : "v"(addr), "i"(OFF));
  return r;
}

// ---------------------------------------------------------------------------
// gemm_v2 (R21 verified): C[m,n] = A[m,k]*B[n,k] (+bias)(+gelu), 128x256.
// ---------------------------------------------------------------------------
template<int GELU, int BIAS, int OUTF32, int CMAP, int KSPLIT>
__global__ __launch_bounds__(512, 4)
void gemm_v2(const short* __restrict__ A, const short* __restrict__ Bm,
             void* __restrict__ Cv, short* __restrict__ C2,
             const float* __restrict__ bias,
             int K, int lda, int ldb, int ldc,
             int Mvalid, int NBmax, int Nwrite)
{
  __shared__ __align__(16) short LDS[36864];

  int Mb = gridDim.x;
  int nwg = gridDim.x * gridDim.y;
  int bid = blockIdx.y * gridDim.x + blockIdx.x;
  int m0, n0;
  if ((Mb & 7) == 0){
    int mslab = Mb >> 3;
    int c = bid & 7, s = bid >> 3;
    int ml = s % mslab, nl = s / mslab;
    m0 = (c*mslab + ml) * 128;
    n0 = nl * 256;
  } else if ((nwg & 7) == 0){
    int chunk = nwg >> 3;
    int b2 = (bid & 7)*chunk + (bid >> 3);
    int by = b2 / Mb;
    m0 = (b2 - by*Mb) * 128;
    n0 = by * 256;
  } else {
    m0 = blockIdx.x * 128;
    n0 = blockIdx.y * 256;
  }
  int kzoff = KSPLIT ? (int)blockIdx.z * K : 0;

  int tid = threadIdx.x, lane = tid & 63, w = tid >> 6;
  int wr = w >> 2, wc = w & 3;
  int rsel = lane & 15, g4 = lane >> 4;

  int sl = lane >> 3;
  int l  = (lane & 7) ^ sl;
  int lc = (l & 3) * 8;
  int lh = l >> 2;
  const short* gA;
  { int r = m0 + w*8 + sl + lh*64; if (r > Mvalid-1) r = Mvalid-1;
    gA = A + (long)r*lda + lc + kzoff; }
  const short* gB0;
  { int r = n0 + w*8 + sl + lh*128; if (r > NBmax-1) r = NBmax-1;
    gB0 = Bm + (long)r*ldb + lc + kzoff; }
  const short* gB1;
  { int r = n0 + 64 + w*8 + sl + lh*128; if (r > NBmax-1) r = NBmax-1;
    gB1 = Bm + (long)r*ldb + lc + kzoff; }
  char* dA  = (char*)LDS + w*1024;
  char* dB0 = (char*)LDS + 8192  + w*1024;
  char* dB1 = (char*)LDS + 16384 + w*1024;

#define GLDS(src, dst) __builtin_amdgcn_global_load_lds( \
      (const __attribute__((address_space(1))) u32*)(src), \
      (__attribute__((address_space(3))) u32*)(dst), 16, 0, 0)
#define STAGE(bo, tau) do { \
    int kb = (tau)*32; \
    GLDS(gA  + kb, dA  + (bo)); \
    GLDS(gB0 + kb, dB0 + (bo)); \
    GLDS(gB1 + kb, dB1 + (bo)); \
  } while(0)

  u32 base = lds_off(LDS);
  u32 aAddr = base + (u32)(rsel*128 + (((wr*4 + g4) ^ (rsel & 7))*16));
  u32 bAddr = base + 8192u
            + (u32)(((wc & 1)*64 + rsel)*128 + ((((wc >> 1)*4 + g4) ^ (rsel & 7))*16));

  int nt = K >> 5;

  f32x4 acc[4][4];
#pragma unroll
  for (int i=0;i<4;i++)
#pragma unroll
    for (int j=0;j<4;j++) acc[i][j] = (f32x4){0.f,0.f,0.f,0.f};

  STAGE(0u, 0);
  if (nt > 1) STAGE(24576u, 1);

  u32 boCur = 0;
#pragma unroll 1
  for (int t=0; t<nt; ++t){
    if (t == nt-1) { asm volatile("s_waitcnt vmcnt(0)" ::: "memory"); }
    else           { asm volatile("s_waitcnt vmcnt(3)" ::: "memory"); }
    asm volatile("s_barrier" ::: "memory");
    u32 aa = aAddr + boCur, bb = bAddr + boCur;
    bf16x8 af[4], bfr[4];
    af[0]  = dsro<0>(aa);    af[1]  = dsro<2048>(aa);
    af[2]  = dsro<4096>(aa); af[3]  = dsro<6144>(aa);
    bfr[0] = dsro<0>(bb);    bfr[1] = dsro<2048>(bb);
    bfr[2] = dsro<4096>(bb); bfr[3] = dsro<6144>(bb);
    if (t+2 < nt){
      u32 boN2 = boCur + 49152u; if (boN2 >= 73728u) boN2 -= 73728u;
      STAGE(boN2, t+2);
    }
    asm volatile("s_waitcnt lgkmcnt(0)" ::: "memory");
    __builtin_amdgcn_sched_barrier(0);
    __builtin_amdgcn_s_setprio(1);
#pragma unroll
    for (int mi=0; mi<4; mi++)
#pragma unroll
      for (int nn=0; nn<4; nn++)
        acc[mi][nn] = __builtin_amdgcn_mfma_f32_16x16x32_bf16(af[mi], bfr[nn], acc[mi][nn], 0, 0, 0);
    __builtin_amdgcn_s_setprio(0);
    boCur += 24576u; if (boCur == 73728u) boCur = 0;
  }
#undef STAGE
#undef GLDS

  int cq = g4 * 4;
  int csel = rsel;
#pragma unroll
  for (int mi=0; mi<4; mi++){
#pragma unroll
    for (int nn=0; nn<4; nn++){
#pragma unroll
      for (int j=0; j<4; j++){
        int gm = m0 + wr*64 + mi*16 + cq + j;
        int gn = n0 + wc*64 + nn*16 + csel;
        if (gm < Mvalid && gn < Nwrite){
          float v = acc[mi][nn][j];
          if (BIAS) v += bias[gn];
          if (GELU) v = 0.5f*v*(1.0f + erff(v*0.70710678118654752f));
          if (CMAP == 0){
            long off = (long)gm*ldc + gn;
            if (KSPLIT) off += (long)blockIdx.z * ((long)Mvalid * ldc);
            if (OUTF32) ((float*)Cv)[off] = v;
            else        ((short*)Cv)[off] = f2bf(v);
          } else if (CMAP == 1){
            int bb2 = gm / 729;
            int jj = gm - bb2*729;
            ((short*)Cv)[((long)bb2*857 + jj)*3072 + gn] = f2bf(v);
          } else {
            if (gn < 1536){
              ((short*)Cv)[(long)gm*1536 + gn] = f2bf(v * 0.1020620726159657f);
            } else {
              int bb2 = gm >> 7, jj = gm & 127;
              C2[((long)bb2*857 + 729 + jj)*3072 + (gn - 1536)] = f2bf(v);
            }
          }
        }
      }
    }
  }
}

// ---------------------------------------------------------------------------
// gemm_qkvx: merged q|kv (blocks [0,576)) + kvx (blocks [576,2784)).
// Same pipeline as gemm_v2; runtime demux of the two verified mappings.
// ---------------------------------------------------------------------------
__global__ __launch_bounds__(512, 4)
void gemm_qkvx(const short* __restrict__ lm, const short* __restrict__ xnorm,
               const short* __restrict__ wTq, const short* __restrict__ wTx,
               short* __restrict__ qb, short* __restrict__ kv,
               const float* __restrict__ biasL)
{
  __shared__ __align__(16) short LDS[36864];

  int bid = blockIdx.x;
  int which = (bid >= 576);           // 0: q|kv, 1: kvx
  const short* A; const short* Bm;
  int m0, n0, Mvalid, NBmax;
  if (!which){
    int mslab = 4;                    // Mb=32
    int c = bid & 7, s = bid >> 3;
    m0 = (c*mslab + s % mslab) * 128;
    n0 = (s / mslab) * 256;
    A = lm; Bm = wTq; Mvalid = 4096; NBmax = 4608;
  } else {
    int local = bid - 576;
    int mslab = 23;                   // Mb=184
    int c = local & 7, s = local >> 3;
    m0 = (c*mslab + s % mslab) * 128;
    n0 = (s / mslab) * 256;
    A = xnorm; Bm = wTx; Mvalid = 23328; NBmax = 3072;
  }

  int tid = threadIdx.x, lane = tid & 63, w = tid >> 6;
  int wr = w >> 2, wc = w & 3;
  int rsel = lane & 15, g4 = lane >> 4;

  int sl = lane >> 3;
  int l  = (lane & 7) ^ sl;
  int lc = (l & 3) * 8;
  int lh = l >> 2;
  const short* gA;
  { int r = m0 + w*8 + sl + lh*64; if (r > Mvalid-1) r = Mvalid-1;
    gA = A + (long)r*1152 + lc; }
  const short* gB0;
  { int r = n0 + w*8 + sl + lh*128; if (r > NBmax-1) r = NBmax-1;
    gB0 = Bm + (long)r*1152 + lc; }
  const short* gB1;
  { int r = n0 + 64 + w*8 + sl + lh*128; if (r > NBmax-1) r = NBmax-1;
    gB1 = Bm + (long)r*1152 + lc; }
  char* dA  = (char*)LDS + w*1024;
  char* dB0 = (char*)LDS + 8192  + w*1024;
  char* dB1 = (char*)LDS + 16384 + w*1024;

#define GLDS(src, dst) __builtin_amdgcn_global_load_lds( \
      (const __attribute__((address_space(1))) u32*)(src), \
      (__attribute__((address_space(3))) u32*)(dst), 16, 0, 0)
#define STAGE(bo, tau) do { \
    int kb = (tau)*32; \
    GLDS(gA  + kb, dA  + (bo)); \
    GLDS(gB0 + kb, dB0 + (bo)); \
    GLDS(gB1 + kb, dB1 + (bo)); \
  } while(0)

  u32 base = lds_off(LDS);
  u32 aAddr = base + (u32)(rsel*128 + (((wr*4 + g4) ^ (rsel & 7))*16));
  u32 bAddr = base + 8192u
            + (u32)(((wc & 1)*64 + rsel)*128 + ((((wc >> 1)*4 + g4) ^ (rsel & 7))*16));

  const int nt = 36;                  // K=1152

  f32x4 acc[4][4];
#pragma unroll
  for (int i=0;i<4;i++)
#pragma unroll
    for (int j=0;j<4;j++) acc[i][j] = (f32x4){0.f,0.f,0.f,0.f};

  STAGE(0u, 0);
  STAGE(24576u, 1);

  u32 boCur = 0;
#pragma unroll 1
  for (int t=0; t<nt; ++t){
    if (t == nt-1) { asm volatile("s_waitcnt vmcnt(0)" ::: "memory"); }
    else           { asm volatile("s_waitcnt vmcnt(3)" ::: "memory"); }
    asm volatile("s_barrier" ::: "memory");
    u32 aa = aAddr + boCur, bb = bAddr + boCur;
    bf16x8 af[4], bfr[4];
    af[0]  = dsro<0>(aa);    af[1]  = dsro<2048>(aa);
    af[2]  = dsro<4096>(aa); af[3]  = dsro<6144>(aa);
    bfr[0] = dsro<0>(bb);    bfr[1] = dsro<2048>(bb);
    bfr[2] = dsro<4096>(bb); bfr[3] = dsro<6144>(bb);
    if (t+2 < nt){
      u32 boN2 = boCur + 49152u; if (boN2 >= 73728u) boN2 -= 73728u;
      STAGE(boN2, t+2);
    }
    asm volatile("s_waitcnt lgkmcnt(0)" ::: "memory");
    __builtin_amdgcn_sched_barrier(0);
    __builtin_amdgcn_s_setprio(1);
#pragma unroll
    for (int mi=0; mi<4; mi++)
#pragma unroll
      for (int nn=0; nn<4; nn++)
        acc[mi][nn] = __builtin_amdgcn_mfma_f32_16x16x32_bf16(af[mi], bfr[nn], acc[mi][nn], 0, 0, 0);
    __builtin_amdgcn_s_setprio(0);
    boCur += 24576u; if (boCur == 73728u) boCur = 0;
  }
#undef STAGE
#undef GLDS

  int cq = g4 * 4;
  int csel = rsel;
#pragma unroll
  for (int mi=0; mi<4; mi++){
#pragma unroll
    for (int nn=0; nn<4; nn++){
#pragma unroll
      for (int j=0; j<4; j++){
        int gm = m0 + wr*64 + mi*16 + cq + j;
        int gn = n0 + wc*64 + nn*16 + csel;
        if (!which){
          if (gm < 4096 && gn < 4608){
            float v = acc[mi][nn][j];
            if (gn < 1536){
              qb[(long)gm*1536 + gn] = f2bf(v * 0.1020620726159657f);
            } else {
              int bb2 = gm >> 7, jj = gm & 127;
              kv[((long)bb2*857 + 729 + jj)*3072 + (gn - 1536)] = f2bf(v);
            }
          }
        } else {
          if (gm < 23328 && gn < 3072){
            float v = acc[mi][nn][j] + biasL[gn];
            int bb2 = gm / 729;
            int jj = gm - bb2*729;
            kv[((long)bb2*857 + jj)*3072 + gn] = f2bf(v);
          }
        }
      }
    }
  }
}

// ---------------------------------------------------------------------------
// red2_ln: lat[r] += p0[r] + p1[r], then (if w) lm[r] = LN(lat[r]; w,b).
// ---------------------------------------------------------------------------
__global__ __launch_bounds__(256)
void red2_ln(float* __restrict__ lat, const float* __restrict__ p, long n,
             short* __restrict__ lm, const float* __restrict__ w,
             const float* __restrict__ b)
{
  const int D = 1152;
  int r = blockIdx.x;
  long rb = (long)r*D;
  int tid = threadIdx.x;
  float s1=0.f, s2=0.f;
  float xv[5];
#pragma unroll
  for (int t=0;t<5;t++){
    int i = tid + t*256;
    float v = 0.f;
    if (i < D){
      v = lat[rb+i] + p[rb+i] + p[n+rb+i];
      lat[rb+i] = v;
    }
    xv[t] = v; s1 += v; s2 += v*v;
  }
  if (!w) return;
#pragma unroll
  for (int o=32;o;o>>=1){ s1 += __shfl_xor(s1,o); s2 += __shfl_xor(s2,o); }
  __shared__ float red[8];
  int wid = tid>>6, lane = tid&63;
  if (lane==0){ red[wid]=s1; red[4+wid]=s2; }
  __syncthreads();
  s1 = red[0]+red[1]+red[2]+red[3];
  s2 = red[4]+red[5]+red[6]+red[7];
  float mu = s1 / D;
  float var = s2 / D - mu*mu;
  float rs = rsqrtf(var + 1e-5f);
#pragma unroll
  for (int t=0;t<5;t++){
    int i = tid + t*256;
    if (i >= D) break;
    lm[rb+i] = f2bf((xv[t]-mu)*rs*w[i] + b[i]);
  }
}

// ---------------------------------------------------------------------------
// Flash attention with fused V-transpose (R19, verified).
// ---------------------------------------------------------------------------
__global__ __launch_bounds__(256)
void flash_attn(const short* __restrict__ qb, const short* __restrict__ kv,
                short* __restrict__ attn)
{
  __shared__ short Kt[96][104];
  __shared__ short Vs[96][104];
  __shared__ short Pb[4][32][104];
  __shared__ float FAC[128];

  int z = blockIdx.x;
  int b = z >> 4, h = z & 15;
  int tid = threadIdx.x;
  int lane = tid & 63;
  int w = tid >> 6;
  int l15 = lane & 15, g4 = lane >> 4;

  bf16x8 qf[2][3];
#pragma unroll
  for (int n=0;n<2;n++)
#pragma unroll
    for (int kf=0;kf<3;kf++)
      qf[n][kf] = *(const bf16x8*)&qb[((long)(b*128 + w*32 + n*16 + l15))*1536
                                     + h*96 + kf*32 + g4*8];

  f32x4 acc[2][6];
#pragma unroll
  for (int i=0;i<2;i++)
#pragma unroll
    for (int j=0;j<6;j++) acc[i][j] = (f32x4){0.f,0.f,0.f,0.f};
  float m_run[2] = {-1e30f, -1e30f};
  float l_run[2] = {0.f, 0.f};

  const short* kvb = kv + (long)b*857*3072 + h*96;
  const short* vvb = kvb + 1536;

  for (int t=0; t<9; ++t){
    int k0 = t*96;
    for (int c = tid; c < 1152; c += 256){
      int r = c / 12;
      int c12 = c - r*12;
      int key = k0 + r; if (key > 856) key = 856;
      *(bf16x8*)&Kt[r][c12*8] = *(const bf16x8*)&kvb[(long)key*3072 + c12*8];
      bf16x8 vv = *(const bf16x8*)&vvb[(long)key*3072 + c12*8];
#pragma unroll
      for (int j=0;j<8;j++) Vs[c12*8 + j][r] = ((short*)&vv)[j];
    }
    __syncthreads();

    f32x4 st[6][2];
#pragma unroll
    for (int m=0;m<6;m++){ st[m][0]=(f32x4){0,0,0,0}; st[m][1]=(f32x4){0,0,0,0}; }
#pragma unroll
    for (int kf=0;kf<3;kf++){
      bf16x8 af[6];
#pragma unroll
      for (int m=0;m<6;m++) af[m] = *(const bf16x8*)&Kt[m*16 + l15][kf*32 + g4*8];
#pragma unroll
      for (int m=0;m<6;m++){
        st[m][0] = __builtin_amdgcn_mfma_f32_16x16x32_bf16(af[m], qf[0][kf], st[m][0], 0,0,0);
        st[m][1] = __builtin_amdgcn_mfma_f32_16x16x32_bf16(af[m], qf[1][kf], st[m][1], 0,0,0);
      }
    }

    if (k0 + 96 > 857){
#pragma unroll
      for (int m=0;m<6;m++)
#pragma unroll
        for (int j=0;j<4;j++){
          if (k0 + m*16 + g4*4 + j > 856){ st[m][0][j] = -1e30f; st[m][1][j] = -1e30f; }
        }
    }

#pragma unroll
    for (int n=0;n<2;n++){
      float mx = -1e30f;
#pragma unroll
      for (int m=0;m<6;m++)
#pragma unroll
        for (int j=0;j<4;j++) mx = fmaxf(mx, st[m][n][j]);
      mx = fmaxf(mx, __shfl_xor(mx, 16));
      mx = fmaxf(mx, __shfl_xor(mx, 32));
      float mn = fmaxf(m_run[n], mx);
      float f  = __expf(m_run[n] - mn);
      m_run[n] = mn;
      float s = 0.f;
#pragma unroll
      for (int m=0;m<6;m++)
#pragma unroll
        for (int j=0;j<4;j++){
          float e = __expf(st[m][n][j] - mn);
          st[m][n][j] = e; s += e;
        }
      s += __shfl_xor(s, 16);
      s += __shfl_xor(s, 32);
      l_run[n] = l_run[n]*f + s;
      if (g4 == 0) FAC[w*32 + n*16 + l15] = f;
    }

#pragma unroll
    for (int m=0;m<6;m++)
#pragma unroll
      for (int n=0;n<2;n++){
        short4 pk;
        pk.x = f2bf(st[m][n][0]); pk.y = f2bf(st[m][n][1]);
        pk.z = f2bf(st[m][n][2]); pk.w = f2bf(st[m][n][3]);
        *(short4*)&Pb[w][n*16 + l15][m*16 + g4*4] = pk;
      }

    {
      float4 fj0 = *(const float4*)&FAC[w*32 +  0 + g4*4];
      float4 fj1 = *(const float4*)&FAC[w*32 + 16 + g4*4];
#pragma unroll
      for (int nn=0;nn<6;nn++){
        acc[0][nn][0] *= fj0.x; acc[0][nn][1] *= fj0.y;
        acc[0][nn][2] *= fj0.z; acc[0][nn][3] *= fj0.w;
        acc[1][nn][0] *= fj1.x; acc[1][nn][1] *= fj1.y;
        acc[1][nn][2] *= fj1.z; acc[1][nn][3] *= fj1.w;
      }
    }

#pragma unroll
    for (int kf=0;kf<3;kf++){
      bf16x8 pa0 = *(const bf16x8*)&Pb[w][ 0 + l15][kf*32 + g4*8];
      bf16x8 pa1 = *(const bf16x8*)&Pb[w][16 + l15][kf*32 + g4*8];
#pragma unroll
      for (int nn=0;nn<6;nn++){
        bf16x8 vb = *(const bf16x8*)&Vs[nn*16 + l15][kf*32 + g4*8];
        acc[0][nn] = __builtin_amdgcn_mfma_f32_16x16x32_bf16(pa0, vb, acc[0][nn], 0,0,0);
        acc[1][nn] = __builtin_amdgcn_mfma_f32_16x16x32_bf16(pa1, vb, acc[1][nn], 0,0,0);
      }
    }
    __syncthreads();
  }

  if (g4 == 0){
    FAC[w*32 +  0 + l15] = 1.0f / l_run[0];
    FAC[w*32 + 16 + l15] = 1.0f / l_run[1];
  }
  float4 li0 = *(const float4*)&FAC[w*32 +  0 + g4*4];
  float4 li1 = *(const float4*)&FAC[w*32 + 16 + g4*4];
  float li[2][4] = {{li0.x,li0.y,li0.z,li0.w},{li1.x,li1.y,li1.z,li1.w}};
#pragma unroll
  for (int mo=0;mo<2;mo++)
#pragma unroll
    for (int nn=0;nn<6;nn++)
#pragma unroll
      for (int j=0;j<4;j++){
        int q = w*32 + mo*16 + g4*4 + j;
        int d = nn*16 + l15;
        attn[((long)(b*128+q))*1536 + h*96 + d] = f2bf(acc[mo][nn][j]*li[mo][j]);
      }
}

// ---------------------------------------------------------------------------
// 128x128 2-phase GEMM (verified r2) for preamble shapes.
// ---------------------------------------------------------------------------
template<int GELU, int BIAS, int RES, int OUTF32>
__global__ __launch_bounds__(256)
void gemm_t(const short* __restrict__ A, const short* __restrict__ B,
            void* __restrict__ C, const float* __restrict__ bias,
            const float* __restrict__ res,
            int K, int lda, int ldb, int ldc,
            int Mvalid, int NBmax, int Nwrite,
            int zdiv, long sA1, long sA2, long sB1, long sB2, long sC1, long sC2,
            float scale)
{
  __shared__ __align__(16) short As[2][128*32];
  __shared__ __align__(16) short Bs[2][128*32];

  int z = blockIdx.z;
  int zq = z / zdiv, zr = z - zq*zdiv;
  const short* Ab = A + zq*sA1 + zr*sA2;
  const short* Bb = B + zq*sB1 + zr*sB2;
  long cOff = zq*sC1 + zr*sC2;
  int m0 = blockIdx.y * 128;
  int n0 = blockIdx.x * 128;
  int tid = threadIdx.x;
  int lane = tid & 63;
  int w = tid >> 6;
  int wm = (w >> 1) * 64, wn = (w & 1) * 64;

  int sr = lane >> 2;
  int sc = (lane & 3) * 8;
  int ar0 = m0 + w*32 + sr;
  int br0 = n0 + w*32 + sr;

  int raA0 = ar0;      if (raA0 > Mvalid-1) raA0 = Mvalid-1;
  int raA1 = ar0 + 16; if (raA1 > Mvalid-1) raA1 = Mvalid-1;
  int rbB0 = br0;      if (rbB0 > NBmax-1) rbB0 = NBmax-1;
  int rbB1 = br0 + 16; if (rbB1 > NBmax-1) rbB1 = NBmax-1;
  const short* gA0 = Ab + (long)raA0*lda + sc;
  const short* gA1 = Ab + (long)raA1*lda + sc;
  const short* gB0 = Bb + (long)rbB0*ldb + sc;
  const short* gB1 = Bb + (long)rbB1*ldb + sc;
  int ldsRow0 = (w*32)*32;
  int ldsRow1 = (w*32 + 16)*32;

  f32x4 acc[4][4];
#pragma unroll
  for (int i=0;i<4;i++)
#pragma unroll
    for (int j=0;j<4;j++) acc[i][j] = (f32x4){0.f,0.f,0.f,0.f};

  auto stage = [&](int buf, int kb){
    __builtin_amdgcn_global_load_lds(
        (const __attribute__((address_space(1))) u32*)(gA0 + kb),
        (__attribute__((address_space(3))) u32*)(&As[buf][ldsRow0]), 16, 0, 0);
    __builtin_amdgcn_global_load_lds(
        (const __attribute__((address_space(1))) u32*)(gA1 + kb),
        (__attribute__((address_space(3))) u32*)(&As[buf][ldsRow1]), 16, 0, 0);
    __builtin_amdgcn_global_load_lds(
        (const __attribute__((address_space(1))) u32*)(gB0 + kb),
        (__attribute__((address_space(3))) u32*)(&Bs[buf][ldsRow0]), 16, 0, 0);
    __builtin_amdgcn_global_load_lds(
        (const __attribute__((address_space(1))) u32*)(gB1 + kb),
        (__attribute__((address_space(3))) u32*)(&Bs[buf][ldsRow1]), 16, 0, 0);
  };

  int nt = K >> 5;
  stage(0, 0);
  __syncthreads();

  int kq = (lane >> 4) * 8;
  int rsel = lane & 15;
  int cur = 0;
  for (int t = 0; t < nt; ++t){
    if (t + 1 < nt) stage(cur ^ 1, (t+1)*32);

    bf16x8 af[4], bfr[4];
#pragma unroll
    for (int m=0;m<4;m++) af[m]  = *(const bf16x8*)&As[cur][(wm + m*16 + rsel)*32 + kq];
#pragma unroll
    for (int n=0;n<4;n++) bfr[n] = *(const bf16x8*)&Bs[cur][(wn + n*16 + rsel)*32 + kq];
#pragma unroll
    for (int m=0;m<4;m++)
#pragma unroll
      for (int n=0;n<4;n++)
        acc[m][n] = __builtin_amdgcn_mfma_f32_16x16x32_bf16(af[m], bfr[n], acc[m][n], 0, 0, 0);

    __syncthreads();
    cur ^= 1;
  }

  int cq = (lane >> 4) * 4;
  int csel = lane & 15;
#pragma unroll
  for (int m=0;m<4;m++){
#pragma unroll
    for (int n=0;n<4;n++){
#pragma unroll
      for (int j=0;j<4;j++){
        int gm = m0 + wm + m*16 + cq + j;
        int gn = n0 + wn + n*16 + csel;
        if (gm < Mvalid && gn < Nwrite){
          float v = acc[m][n][j] * scale;
          if (BIAS) v += bias[gn];
          if (GELU) v = 0.5f*v*(1.0f + erff(v*0.70710678118654752f));
          long off = cOff + (long)gm*ldc + gn;
          if (OUTF32){
            float rv = RES ? res[off] : 0.0f;
            ((float*)C)[off] = v + rv;
          } else {
            ((short*)C)[off] = f2bf(v);
          }
        }
      }
    }
  }
}

// ---------------------------------------------------------------------------
__global__ __launch_bounds__(256)
void convT(const float* __restrict__ in, short* __restrict__ out,
           int K, int N, const float* __restrict__ s)
{
  __shared__ float tile[32][33];
  int kb = blockIdx.y*32, nb = blockIdx.x*32;
  int tx = threadIdx.x & 31, ty = threadIdx.x >> 5;
  for (int i = ty; i < 32; i += 8){
    int k = kb + i, n = nb + tx;
    float v = 0.f;
    if (k < K && n < N){ v = in[(long)k*N + n]; if (s) v *= s[k]; }
    tile[i][tx] = v;
  }
  __syncthreads();
  for (int i = ty; i < 32; i += 8){
    int n = nb + i, k = kb + tx;
    if (n < N && k < K) out[(long)n*K + k] = f2bf(tile[tx][i]);
  }
}

// merged per-layer transpose: Wq | Wkv(dual) | Wo | fw1 | fw2, 17280 blocks.
__global__ __launch_bounds__(256)
void convT_wall(const float* __restrict__ Wq, const float* __restrict__ Wkv,
                const float* __restrict__ s,
                const float* __restrict__ Wo, const float* __restrict__ fw1,
                const float* __restrict__ fw2,
                short* __restrict__ outQ, short* __restrict__ outKx,
                short* __restrict__ outK, short* __restrict__ outWo,
                short* __restrict__ outF1, short* __restrict__ outF2)
{
  __shared__ float tile[32][33];
  __shared__ float sv[32];
  int b = blockIdx.x;
  int tx = threadIdx.x & 31, ty = threadIdx.x >> 5;
  if (b < 1728){
    // Wq: K=1152 (36 kt), N=1536 (48 nt)
    int bx = b % 48, byy = b / 48;
    int kb = byy*32, nb = bx*32;
    for (int i = ty; i < 32; i += 8)
      tile[i][tx] = Wq[(long)(kb + i)*1536 + nb + tx];
    __syncthreads();
    for (int i = ty; i < 32; i += 8)
      outQ[(long)(nb + i)*1152 + kb + tx] = f2bf(tile[tx][i]);
  } else if (b < 5184){
    // Wkv dual: K=1152 (36), N=3072 (96)
    int b2 = b - 1728;
    int bx = b2 % 96, byy = b2 / 96;
    int kb = byy*32, nb = bx*32;
    if (threadIdx.x < 32) sv[threadIdx.x] = s[kb + threadIdx.x];
    for (int i = ty; i < 32; i += 8)
      tile[i][tx] = Wkv[(long)(kb + i)*3072 + nb + tx];
    __syncthreads();
    for (int i = ty; i < 32; i += 8){
      float v = tile[tx][i];
      long o = (long)(nb + i)*1152 + kb + tx;
      outK[o]  = f2bf(v);
      outKx[o] = f2bf(v * sv[tx]);
    }
  } else {
    const float* in; short* out; int K, N, kb, nb;
    if (b < 6912){
      int b3 = b - 5184;
      in = Wo; out = outWo; K = 1536; N = 1152;
      nb = (b3 % 36)*32; kb = (b3 / 36)*32;
    } else if (b < 12096){
      int b4 = b - 6912;
      in = fw1; out = outF1; K = 1152; N = 4608;
      nb = (b4 % 144)*32; kb = (b4 / 144)*32;
    } else {
      int b5 = b - 12096;
      in = fw2; out = outF2; K = 4608; N = 1152;
      nb = (b5 % 36)*32; kb = (b5 / 36)*32;
    }
    for (int i = ty; i < 32; i += 8)
      tile[i][tx] = in[(long)(kb + i)*N + nb + tx];
    __syncthreads();
    for (int i = ty; i < 32; i += 8)
      out[(long)(nb + i)*K + kb + tx] = f2bf(tile[tx][i]);
  }
}

// biasf[L][n] = sum_k nm_b[L][k] * Wkv[L][k*3072+n]  (all layers, one dispatch)
__global__ __launch_bounds__(256)
void biasfold6(const float* __restrict__ Wkv, const float* __restrict__ nm_b,
               float* __restrict__ outb)
{
  int L = blockIdx.y;
  int n = blockIdx.x*256 + threadIdx.x;
  const float* W = Wkv + (size_t)L*1152*3072;
  const float* bvec = nm_b + L*1152;
  float s = 0.f;
  for (int k=0;k<1152;k++) s += bvec[k]*W[(long)k*3072 + n];
  outb[L*3072 + n] = s;
}

__global__ __launch_bounds__(256)
void cvt_bf16x4(const float* __restrict__ in, short* __restrict__ o, long n)
{
  long i = ((long)blockIdx.x*256 + threadIdx.x)*4;
  if (i >= n) return;
  float4 v = *(const float4*)(in + i);
  short4 s4;
  s4.x = f2bf(v.x); s4.y = f2bf(v.y); s4.z = f2bf(v.z); s4.w = f2bf(v.w);
  *(short4*)&o[i] = s4;
}

__global__ __launch_bounds__(256)
void latcopy(const float* __restrict__ latents, float* __restrict__ lat)
{
  int idx = blockIdx.x*256 + threadIdx.x;
  int d = idx % 1152; int j = (idx / 1152) % 64; int b = idx / (1152*64);
  lat[((long)b*128 + j)*1152 + d] = latents[j*1152 + d];
}

template<int OUTF32>
__global__ __launch_bounds__(256)
void ln_k(const float* __restrict__ in, void* __restrict__ outp,
          const float* __restrict__ w, const float* __restrict__ b,
          int grpSel, int grpStride)
{
  const int D = 1152;
  int r = blockIdx.x;
  long ir = (long)(r / grpSel)*grpStride + (r % grpSel);
  const float* x = in + ir*D;
  int tid = threadIdx.x;
  float s1=0.f, s2=0.f;
  float xv[5];
#pragma unroll
  for (int t=0;t<5;t++){
    int i = tid + t*256;
    xv[t] = (i < D) ? x[i] : 0.f;
    s1 += xv[t]; s2 += xv[t]*xv[t];
  }
#pragma unroll
  for (int o=32;o;o>>=1){ s1 += __shfl_xor(s1,o); s2 += __shfl_xor(s2,o); }
  __shared__ float red[8];
  int wid = tid>>6, lane = tid&63;
  if (lane==0){ red[wid]=s1; red[4+wid]=s2; }
  __syncthreads();
  s1 = red[0]+red[1]+red[2]+red[3];
  s2 = red[4]+red[5]+red[6]+red[7];
  float mu = s1 / D;
  float var = s2 / D - mu*mu;
  float rs = rsqrtf(var + 1e-5f);
#pragma unroll
  for (int t=0;t<5;t++){
    int i = tid + t*256;
    if (i >= D) break;
    float v = (xv[t]-mu)*rs;
    if (w) v = v*w[i] + b[i];
    if (OUTF32) ((float*)outp)[(long)r*D + i] = v;
    else        ((short*)outp)[(long)r*D + i] = f2bf(v);
  }
}

// ---------------------------------------------------------------------------

extern "C" void kernel_launch(void* const* d_in, const int* in_sizes, int n_in,
                              void* d_out, int out_size, void* d_ws, size_t ws_size,
                              hipStream_t stream)
{
  const float* x      = (const float*)d_in[0];
  const float* tein   = (const float*)d_in[1];
  const float* lat0   = (const float*)d_in[2];
  const float* txt_w1 = (const float*)d_in[3];
  const float* txt_b1 = (const float*)d_in[4];
  const float* txt_w2 = (const float*)d_in[5];
  const float* txt_b2 = (const float*)d_in[6];
  const float* nm_w   = (const float*)d_in[7];
  const float* nm_b   = (const float*)d_in[8];
  const float* nl_w   = (const float*)d_in[9];
  const float* nl_b   = (const float*)d_in[10];
  const float* Wq     = (const float*)d_in[11];
  const float* Wkv    = (const float*)d_in[12];
  const float* Wo     = (const float*)d_in[13];
  const float* ffln_w = (const float*)d_in[14];
  const float* ffln_b = (const float*)d_in[15];
  const float* ff_w1  = (const float*)d_in[16];
  const float* ff_w2  = (const float*)d_in[17];
  const float* oln_w  = (const float*)d_in[18];
  const float* oln_b  = (const float*)d_in[19];
  float* out = (float*)d_out;
  (void)in_sizes; (void)n_in; (void)out_size; (void)ws_size;

  char* base = (char*)d_ws;
  size_t off = 0;
  auto alloc = [&](size_t bytes)->char*{
    char* r = base + off;
    off += (bytes + 255) & ~(size_t)255;
    return r;
  };
  short* wT    = (short*)alloc(4608ULL*1152*2);   // Wq^T | Wkv^T
  short* wTx   = (short*)alloc(3072ULL*1152*2);   // nm-scaled Wkv^T
  short* wTo   = (short*)alloc(1152ULL*1536*2);   // Wo^T
  short* wTf1  = (short*)alloc(4608ULL*1152*2);   // fw1^T
  short* wTf2  = (short*)alloc(1152ULL*4608*2);   // fw2^T
  float* biasf = (float*)alloc(6*3072*4);
  float* ppart = (float*)alloc(2ULL*4096*1152*4);
  short* xnorm = (short*)alloc(23328ULL*1152*2);
  float* lat   = (float*)alloc(4096ULL*1152*4);
  short* lm    = (short*)alloc(4096ULL*1152*2);
  short* qb    = (short*)alloc(4096ULL*1536*2);
  short* kv    = (short*)alloc(27424ULL*3072*2);
  short* SP    = (short*)alloc(2048ULL*4096*2 + 2048ULL*1152*2);
  short* attn  = (short*)alloc(4096ULL*1536*2);
  short* ffh   = (short*)alloc(4096ULL*4608*2);
  short* txtin = SP;
  short* txth  = SP + 2048ULL*4096;

  // ---- preamble ----
  cvt_bf16x4<<<8192,256,0,stream>>>(tein, txtin, 2048LL*4096);
  convT<<<dim3(36,128),256,0,stream>>>(txt_w1, wT, 4096, 1152, nullptr);
  gemm_t<1,1,0,0><<<dim3(9,16,1),256,0,stream>>>(txtin, wT, txth, txt_b1, nullptr,
      4096,4096,4096,1152, 2048,1152,1152, 1, 0,0,0,0,0,0, 1.f);
  convT<<<dim3(36,36),256,0,stream>>>(txt_w2, wT, 1152, 1152, nullptr);
  gemm_t<0,1,0,1><<<dim3(9,1,32),256,0,stream>>>(txth, wT, lat + 64*1152, txt_b2, nullptr,
      1152,1152,1152,1152, 64,1152,1152, 1, 64L*1152,0, 0,0, 128L*1152,0, 1.f);
  latcopy<<<9216,256,0,stream>>>(lat0, lat);

  ln_k<0><<<23328,256,0,stream>>>(x, xnorm, nullptr, nullptr, 1<<28, 0);
  ln_k<0><<<4096,256,0,stream>>>(lat, lm, nl_w, nl_b, 1<<28, 0);
  biasfold6<<<dim3(12,6),256,0,stream>>>(Wkv, nm_b, biasf);

  for (int L=0; L<6; L++){
    const float* WqL  = Wq    + (size_t)L*1152*1536;
    const float* WkvL = Wkv   + (size_t)L*1152*3072;
    const float* WoL  = Wo    + (size_t)L*1536*1152;
    const float* fw1  = ff_w1 + (size_t)L*1152*4608;
    const float* fw2  = ff_w2 + (size_t)L*4608*1152;
    int Ln = (L+1 < 6) ? (L+1) : 5;

    // all five weight transposes, one dispatch
    convT_wall<<<17280,256,0,stream>>>(WqL, WkvL, nm_w + L*1152, WoL, fw1, fw2,
        wT, wTx, wT + 1536*1152, wTo, wTf1, wTf2);

    // merged q|kv + kvx (independent outputs; both feed flash)
    gemm_qkvx<<<2784,512,0,stream>>>(lm, xnorm, wT, wTx, qb, kv, biasf + L*3072);

    flash_attn<<<512,256,0,stream>>>(qb, kv, attn);

    gemm_v2<0,0,1,0,1><<<dim3(32,5,2),512,0,stream>>>(attn, wTo, ppart, nullptr, nullptr,
        768,1536,1536,1152, 4096, 1152, 1152);
    red2_ln<<<4096,256,0,stream>>>(lat, ppart, 4096L*1152, lm,
        ffln_w + L*1152, ffln_b + L*1152);

    gemm_v2<1,0,0,0,0><<<dim3(32,18),512,0,stream>>>(lm, wTf1, ffh, nullptr, nullptr,
        1152,1152,1152,4608, 4096, 4608, 4608);
    gemm_v2<0,0,1,0,1><<<dim3(32,5,2),512,0,stream>>>(ffh, wTf2, ppart, nullptr, nullptr,
        2304,4608,4608,1152, 4096, 1152, 1152);
    red2_ln<<<4096,256,0,stream>>>(lat, ppart, 4096L*1152, lm,
        (L+1 < 6) ? (nl_w + Ln*1152) : nullptr, nl_b + Ln*1152);
  }

  ln_k<1><<<2048,256,0,stream>>>(lat, out, oln_w, oln_b, 64, 128);
}

// Round 23
// 3630.984 us; speedup vs baseline: 1.0355x; 1.0355x over previous
//
#include <hip/hip_runtime.h>
#include <hip/hip_bf16.h>
#include <math.h>

// InstructPerceiverResampler on MI355X (gfx950).
// Round 23 (base = R21, 3670us): SALVAGE R22 — keep the merged gemm_qkvx
// (280us vs ~312us for the split pair; counters confirmed the merge won),
// REVERT convT_wall: convT_qkv stays at loop top, convT_ffo stays AFTER
// flash_attn so wTo/wTf1/wTf2 are L3-hot for the GEMMs that read them
// (R22's loop-top placement let gemm_qkvx's 640MB flush them -> +47us/layer).

typedef __attribute__((ext_vector_type(4))) float f32x4;
typedef __attribute__((ext_vector_type(8))) short bf16x8;
typedef unsigned int u32;

#define DEV __device__ __forceinline__

DEV float bf2f(short s){ union{u32 u; float f;} v; v.u = ((u32)(unsigned short)s) << 16; return v.f; }
DEV short f2bf(float f){
  union{float f; u32 u;} v; v.f = f;
  u32 r = (v.u + 0x7FFFu + ((v.u >> 16) & 1u)) >> 16;
  return (short)r;
}

DEV u32 lds_off(const short* p){
  return (u32)(uintptr_t)(__attribute__((address_space(3))) const short*)p;
}
template<int OFF>
DEV bf16x8 dsro(u32 addr){
  bf16x8 r;
  asm volatile("ds_read_b128 %0, %1 offset:%2" : "=v"(r) : "v"(addr), "i"(OFF));
  return r;
}

// ---------------------------------------------------------------------------
// gemm_v2 (R21 verified): C[m,n] = A[m,k]*B[n,k] (+bias)(+gelu), 128x256.
// ---------------------------------------------------------------------------
template<int GELU, int BIAS, int OUTF32, int CMAP, int KSPLIT>
__global__ __launch_bounds__(512, 4)
void gemm_v2(const short* __restrict__ A, const short* __restrict__ Bm,
             void* __restrict__ Cv, short* __restrict__ C2,
             const float* __restrict__ bias,
             int K, int lda, int ldb, int ldc,
             int Mvalid, int NBmax, int Nwrite)
{
  __shared__ __align__(16) short LDS[36864];

  int Mb = gridDim.x;
  int nwg = gridDim.x * gridDim.y;
  int bid = blockIdx.y * gridDim.x + blockIdx.x;
  int m0, n0;
  if ((Mb & 7) == 0){
    int mslab = Mb >> 3;
    int c = bid & 7, s = bid >> 3;
    int ml = s % mslab, nl = s / mslab;
    m0 = (c*mslab + ml) * 128;
    n0 = nl * 256;
  } else if ((nwg & 7) == 0){
    int chunk = nwg >> 3;
    int b2 = (bid & 7)*chunk + (bid >> 3);
    int by = b2 / Mb;
    m0 = (b2 - by*Mb) * 128;
    n0 = by * 256;
  } else {
    m0 = blockIdx.x * 128;
    n0 = blockIdx.y * 256;
  }
  int kzoff = KSPLIT ? (int)blockIdx.z * K : 0;

  int tid = threadIdx.x, lane = tid & 63, w = tid >> 6;
  int wr = w >> 2, wc = w & 3;
  int rsel = lane & 15, g4 = lane >> 4;

  int sl = lane >> 3;
  int l  = (lane & 7) ^ sl;
  int lc = (l & 3) * 8;
  int lh = l >> 2;
  const short* gA;
  { int r = m0 + w*8 + sl + lh*64; if (r > Mvalid-1) r = Mvalid-1;
    gA = A + (long)r*lda + lc + kzoff; }
  const short* gB0;
  { int r = n0 + w*8 + sl + lh*128; if (r > NBmax-1) r = NBmax-1;
    gB0 = Bm + (long)r*ldb + lc + kzoff; }
  const short* gB1;
  { int r = n0 + 64 + w*8 + sl + lh*128; if (r > NBmax-1) r = NBmax-1;
    gB1 = Bm + (long)r*ldb + lc + kzoff; }
  char* dA  = (char*)LDS + w*1024;
  char* dB0 = (char*)LDS + 8192  + w*1024;
  char* dB1 = (char*)LDS + 16384 + w*1024;

#define GLDS(src, dst) __builtin_amdgcn_global_load_lds( \
      (const __attribute__((address_space(1))) u32*)(src), \
      (__attribute__((address_space(3))) u32*)(dst), 16, 0, 0)
#define STAGE(bo, tau) do { \
    int kb = (tau)*32; \
    GLDS(gA  + kb, dA  + (bo)); \
    GLDS(gB0 + kb, dB0 + (bo)); \
    GLDS(gB1 + kb, dB1 + (bo)); \
  } while(0)

  u32 base = lds_off(LDS);
  u32 aAddr = base + (u32)(rsel*128 + (((wr*4 + g4) ^ (rsel & 7))*16));
  u32 bAddr = base + 8192u
            + (u32)(((wc & 1)*64 + rsel)*128 + ((((wc >> 1)*4 + g4) ^ (rsel & 7))*16));

  int nt = K >> 5;

  f32x4 acc[4][4];
#pragma unroll
  for (int i=0;i<4;i++)
#pragma unroll
    for (int j=0;j<4;j++) acc[i][j] = (f32x4){0.f,0.f,0.f,0.f};

  STAGE(0u, 0);
  if (nt > 1) STAGE(24576u, 1);

  u32 boCur = 0;
#pragma unroll 1
  for (int t=0; t<nt; ++t){
    if (t == nt-1) { asm volatile("s_waitcnt vmcnt(0)" ::: "memory"); }
    else           { asm volatile("s_waitcnt vmcnt(3)" ::: "memory"); }
    asm volatile("s_barrier" ::: "memory");
    u32 aa = aAddr + boCur, bb = bAddr + boCur;
    bf16x8 af[4], bfr[4];
    af[0]  = dsro<0>(aa);    af[1]  = dsro<2048>(aa);
    af[2]  = dsro<4096>(aa); af[3]  = dsro<6144>(aa);
    bfr[0] = dsro<0>(bb);    bfr[1] = dsro<2048>(bb);
    bfr[2] = dsro<4096>(bb); bfr[3] = dsro<6144>(bb);
    if (t+2 < nt){
      u32 boN2 = boCur + 49152u; if (boN2 >= 73728u) boN2 -= 73728u;
      STAGE(boN2, t+2);
    }
    asm volatile("s_waitcnt lgkmcnt(0)" ::: "memory");
    __builtin_amdgcn_sched_barrier(0);
    __builtin_amdgcn_s_setprio(1);
#pragma unroll
    for (int mi=0; mi<4; mi++)
#pragma unroll
      for (int nn=0; nn<4; nn++)
        acc[mi][nn] = __builtin_amdgcn_mfma_f32_16x16x32_bf16(af[mi], bfr[nn], acc[mi][nn], 0, 0, 0);
    __builtin_amdgcn_s_setprio(0);
    boCur += 24576u; if (boCur == 73728u) boCur = 0;
  }
#undef STAGE
#undef GLDS

  int cq = g4 * 4;
  int csel = rsel;
#pragma unroll
  for (int mi=0; mi<4; mi++){
#pragma unroll
    for (int nn=0; nn<4; nn++){
#pragma unroll
      for (int j=0; j<4; j++){
        int gm = m0 + wr*64 + mi*16 + cq + j;
        int gn = n0 + wc*64 + nn*16 + csel;
        if (gm < Mvalid && gn < Nwrite){
          float v = acc[mi][nn][j];
          if (BIAS) v += bias[gn];
          if (GELU) v = 0.5f*v*(1.0f + erff(v*0.70710678118654752f));
          if (CMAP == 0){
            long off = (long)gm*ldc + gn;
            if (KSPLIT) off += (long)blockIdx.z * ((long)Mvalid * ldc);
            if (OUTF32) ((float*)Cv)[off] = v;
            else        ((short*)Cv)[off] = f2bf(v);
          } else if (CMAP == 1){
            int bb2 = gm / 729;
            int jj = gm - bb2*729;
            ((short*)Cv)[((long)bb2*857 + jj)*3072 + gn] = f2bf(v);
          } else {
            if (gn < 1536){
              ((short*)Cv)[(long)gm*1536 + gn] = f2bf(v * 0.1020620726159657f);
            } else {
              int bb2 = gm >> 7, jj = gm & 127;
              C2[((long)bb2*857 + 729 + jj)*3072 + (gn - 1536)] = f2bf(v);
            }
          }
        }
      }
    }
  }
}

// ---------------------------------------------------------------------------
// gemm_qkvx (R22 verified-correct, counters showed the merge is faster):
// blocks [0,576) = q|kv, [576,2784) = kvx.
// ---------------------------------------------------------------------------
__global__ __launch_bounds__(512, 4)
void gemm_qkvx(const short* __restrict__ lm, const short* __restrict__ xnorm,
               const short* __restrict__ wTq, const short* __restrict__ wTx,
               short* __restrict__ qb, short* __restrict__ kv,
               const float* __restrict__ biasL)
{
  __shared__ __align__(16) short LDS[36864];

  int bid = blockIdx.x;
  int which = (bid >= 576);
  const short* A; const short* Bm;
  int m0, n0, Mvalid, NBmax;
  if (!which){
    int mslab = 4;
    int c = bid & 7, s = bid >> 3;
    m0 = (c*mslab + s % mslab) * 128;
    n0 = (s / mslab) * 256;
    A = lm; Bm = wTq; Mvalid = 4096; NBmax = 4608;
  } else {
    int local = bid - 576;
    int mslab = 23;
    int c = local & 7, s = local >> 3;
    m0 = (c*mslab + s % mslab) * 128;
    n0 = (s / mslab) * 256;
    A = xnorm; Bm = wTx; Mvalid = 23328; NBmax = 3072;
  }

  int tid = threadIdx.x, lane = tid & 63, w = tid >> 6;
  int wr = w >> 2, wc = w & 3;
  int rsel = lane & 15, g4 = lane >> 4;

  int sl = lane >> 3;
  int l  = (lane & 7) ^ sl;
  int lc = (l & 3) * 8;
  int lh = l >> 2;
  const short* gA;
  { int r = m0 + w*8 + sl + lh*64; if (r > Mvalid-1) r = Mvalid-1;
    gA = A + (long)r*1152 + lc; }
  const short* gB0;
  { int r = n0 + w*8 + sl + lh*128; if (r > NBmax-1) r = NBmax-1;
    gB0 = Bm + (long)r*1152 + lc; }
  const short* gB1;
  { int r = n0 + 64 + w*8 + sl + lh*128; if (r > NBmax-1) r = NBmax-1;
    gB1 = Bm + (long)r*1152 + lc; }
  char* dA  = (char*)LDS + w*1024;
  char* dB0 = (char*)LDS + 8192  + w*1024;
  char* dB1 = (char*)LDS + 16384 + w*1024;

#define GLDS(src, dst) __builtin_amdgcn_global_load_lds( \
      (const __attribute__((address_space(1))) u32*)(src), \
      (__attribute__((address_space(3))) u32*)(dst), 16, 0, 0)
#define STAGE(bo, tau) do { \
    int kb = (tau)*32; \
    GLDS(gA  + kb, dA  + (bo)); \
    GLDS(gB0 + kb, dB0 + (bo)); \
    GLDS(gB1 + kb, dB1 + (bo)); \
  } while(0)

  u32 base = lds_off(LDS);
  u32 aAddr = base + (u32)(rsel*128 + (((wr*4 + g4) ^ (rsel & 7))*16));
  u32 bAddr = base + 8192u
            + (u32)(((wc & 1)*64 + rsel)*128 + ((((wc >> 1)*4 + g4) ^ (rsel & 7))*16));

  const int nt = 36;

  f32x4 acc[4][4];
#pragma unroll
  for (int i=0;i<4;i++)
#pragma unroll
    for (int j=0;j<4;j++) acc[i][j] = (f32x4){0.f,0.f,0.f,0.f};

  STAGE(0u, 0);
  STAGE(24576u, 1);

  u32 boCur = 0;
#pragma unroll 1
  for (int t=0; t<nt; ++t){
    if (t == nt-1) { asm volatile("s_waitcnt vmcnt(0)" ::: "memory"); }
    else           { asm volatile("s_waitcnt vmcnt(3)" ::: "memory"); }
    asm volatile("s_barrier" ::: "memory");
    u32 aa = aAddr + boCur, bb = bAddr + boCur;
    bf16x8 af[4], bfr[4];
    af[0]  = dsro<0>(aa);    af[1]  = dsro<2048>(aa);
    af[2]  = dsro<4096>(aa); af[3]  = dsro<6144>(aa);
    bfr[0] = dsro<0>(bb);    bfr[1] = dsro<2048>(bb);
    bfr[2] = dsro<4096>(bb); bfr[3] = dsro<6144>(bb);
    if (t+2 < nt){
      u32 boN2 = boCur + 49152u; if (boN2 >= 73728u) boN2 -= 73728u;
      STAGE(boN2, t+2);
    }
    asm volatile("s_waitcnt lgkmcnt(0)" ::: "memory");
    __builtin_amdgcn_sched_barrier(0);
    __builtin_amdgcn_s_setprio(1);
#pragma unroll
    for (int mi=0; mi<4; mi++)
#pragma unroll
      for (int nn=0; nn<4; nn++)
        acc[mi][nn] = __builtin_amdgcn_mfma_f32_16x16x32_bf16(af[mi], bfr[nn], acc[mi][nn], 0, 0, 0);
    __builtin_amdgcn_s_setprio(0);
    boCur += 24576u; if (boCur == 73728u) boCur = 0;
  }
#undef STAGE
#undef GLDS

  int cq = g4 * 4;
  int csel = rsel;
#pragma unroll
  for (int mi=0; mi<4; mi++){
#pragma unroll
    for (int nn=0; nn<4; nn++){
#pragma unroll
      for (int j=0; j<4; j++){
        int gm = m0 + wr*64 + mi*16 + cq + j;
        int gn = n0 + wc*64 + nn*16 + csel;
        if (!which){
          if (gm < 4096 && gn < 4608){
            float v = acc[mi][nn][j];
            if (gn < 1536){
              qb[(long)gm*1536 + gn] = f2bf(v * 0.1020620726159657f);
            } else {
              int bb2 = gm >> 7, jj = gm & 127;
              kv[((long)bb2*857 + 729 + jj)*3072 + (gn - 1536)] = f2bf(v);
            }
          }
        } else {
          if (gm < 23328 && gn < 3072){
            float v = acc[mi][nn][j] + biasL[gn];
            int bb2 = gm / 729;
            int jj = gm - bb2*729;
            kv[((long)bb2*857 + jj)*3072 + gn] = f2bf(v);
          }
        }
      }
    }
  }
}

// ---------------------------------------------------------------------------
// red2_ln: lat[r] += p0[r] + p1[r], then (if w) lm[r] = LN(lat[r]; w,b).
// ---------------------------------------------------------------------------
__global__ __launch_bounds__(256)
void red2_ln(float* __restrict__ lat, const float* __restrict__ p, long n,
             short* __restrict__ lm, const float* __restrict__ w,
             const float* __restrict__ b)
{
  const int D = 1152;
  int r = blockIdx.x;
  long rb = (long)r*D;
  int tid = threadIdx.x;
  float s1=0.f, s2=0.f;
  float xv[5];
#pragma unroll
  for (int t=0;t<5;t++){
    int i = tid + t*256;
    float v = 0.f;
    if (i < D){
      v = lat[rb+i] + p[rb+i] + p[n+rb+i];
      lat[rb+i] = v;
    }
    xv[t] = v; s1 += v; s2 += v*v;
  }
  if (!w) return;
#pragma unroll
  for (int o=32;o;o>>=1){ s1 += __shfl_xor(s1,o); s2 += __shfl_xor(s2,o); }
  __shared__ float red[8];
  int wid = tid>>6, lane = tid&63;
  if (lane==0){ red[wid]=s1; red[4+wid]=s2; }
  __syncthreads();
  s1 = red[0]+red[1]+red[2]+red[3];
  s2 = red[4]+red[5]+red[6]+red[7];
  float mu = s1 / D;
  float var = s2 / D - mu*mu;
  float rs = rsqrtf(var + 1e-5f);
#pragma unroll
  for (int t=0;t<5;t++){
    int i = tid + t*256;
    if (i >= D) break;
    lm[rb+i] = f2bf((xv[t]-mu)*rs*w[i] + b[i]);
  }
}

// ---------------------------------------------------------------------------
// Flash attention with fused V-transpose (R19, verified).
// ---------------------------------------------------------------------------
__global__ __launch_bounds__(256)
void flash_attn(const short* __restrict__ qb, const short* __restrict__ kv,
                short* __restrict__ attn)
{
  __shared__ short Kt[96][104];
  __shared__ short Vs[96][104];
  __shared__ short Pb[4][32][104];
  __shared__ float FAC[128];

  int z = blockIdx.x;
  int b = z >> 4, h = z & 15;
  int tid = threadIdx.x;
  int lane = tid & 63;
  int w = tid >> 6;
  int l15 = lane & 15, g4 = lane >> 4;

  bf16x8 qf[2][3];
#pragma unroll
  for (int n=0;n<2;n++)
#pragma unroll
    for (int kf=0;kf<3;kf++)
      qf[n][kf] = *(const bf16x8*)&qb[((long)(b*128 + w*32 + n*16 + l15))*1536
                                     + h*96 + kf*32 + g4*8];

  f32x4 acc[2][6];
#pragma unroll
  for (int i=0;i<2;i++)
#pragma unroll
    for (int j=0;j<6;j++) acc[i][j] = (f32x4){0.f,0.f,0.f,0.f};
  float m_run[2] = {-1e30f, -1e30f};
  float l_run[2] = {0.f, 0.f};

  const short* kvb = kv + (long)b*857*3072 + h*96;
  const short* vvb = kvb + 1536;

  for (int t=0; t<9; ++t){
    int k0 = t*96;
    for (int c = tid; c < 1152; c += 256){
      int r = c / 12;
      int c12 = c - r*12;
      int key = k0 + r; if (key > 856) key = 856;
      *(bf16x8*)&Kt[r][c12*8] = *(const bf16x8*)&kvb[(long)key*3072 + c12*8];
      bf16x8 vv = *(const bf16x8*)&vvb[(long)key*3072 + c12*8];
#pragma unroll
      for (int j=0;j<8;j++) Vs[c12*8 + j][r] = ((short*)&vv)[j];
    }
    __syncthreads();

    f32x4 st[6][2];
#pragma unroll
    for (int m=0;m<6;m++){ st[m][0]=(f32x4){0,0,0,0}; st[m][1]=(f32x4){0,0,0,0}; }
#pragma unroll
    for (int kf=0;kf<3;kf++){
      bf16x8 af[6];
#pragma unroll
      for (int m=0;m<6;m++) af[m] = *(const bf16x8*)&Kt[m*16 + l15][kf*32 + g4*8];
#pragma unroll
      for (int m=0;m<6;m++){
        st[m][0] = __builtin_amdgcn_mfma_f32_16x16x32_bf16(af[m], qf[0][kf], st[m][0], 0,0,0);
        st[m][1] = __builtin_amdgcn_mfma_f32_16x16x32_bf16(af[m], qf[1][kf], st[m][1], 0,0,0);
      }
    }

    if (k0 + 96 > 857){
#pragma unroll
      for (int m=0;m<6;m++)
#pragma unroll
        for (int j=0;j<4;j++){
          if (k0 + m*16 + g4*4 + j > 856){ st[m][0][j] = -1e30f; st[m][1][j] = -1e30f; }
        }
    }

#pragma unroll
    for (int n=0;n<2;n++){
      float mx = -1e30f;
#pragma unroll
      for (int m=0;m<6;m++)
#pragma unroll
        for (int j=0;j<4;j++) mx = fmaxf(mx, st[m][n][j]);
      mx = fmaxf(mx, __shfl_xor(mx, 16));
      mx = fmaxf(mx, __shfl_xor(mx, 32));
      float mn = fmaxf(m_run[n], mx);
      float f  = __expf(m_run[n] - mn);
      m_run[n] = mn;
      float s = 0.f;
#pragma unroll
      for (int m=0;m<6;m++)
#pragma unroll
        for (int j=0;j<4;j++){
          float e = __expf(st[m][n][j] - mn);
          st[m][n][j] = e; s += e;
        }
      s += __shfl_xor(s, 16);
      s += __shfl_xor(s, 32);
      l_run[n] = l_run[n]*f + s;
      if (g4 == 0) FAC[w*32 + n*16 + l15] = f;
    }

#pragma unroll
    for (int m=0;m<6;m++)
#pragma unroll
      for (int n=0;n<2;n++){
        short4 pk;
        pk.x = f2bf(st[m][n][0]); pk.y = f2bf(st[m][n][1]);
        pk.z = f2bf(st[m][n][2]); pk.w = f2bf(st[m][n][3]);
        *(short4*)&Pb[w][n*16 + l15][m*16 + g4*4] = pk;
      }

    {
      float4 fj0 = *(const float4*)&FAC[w*32 +  0 + g4*4];
      float4 fj1 = *(const float4*)&FAC[w*32 + 16 + g4*4];
#pragma unroll
      for (int nn=0;nn<6;nn++){
        acc[0][nn][0] *= fj0.x; acc[0][nn][1] *= fj0.y;
        acc[0][nn][2] *= fj0.z; acc[0][nn][3] *= fj0.w;
        acc[1][nn][0] *= fj1.x; acc[1][nn][1] *= fj1.y;
        acc[1][nn][2] *= fj1.z; acc[1][nn][3] *= fj1.w;
      }
    }

#pragma unroll
    for (int kf=0;kf<3;kf++){
      bf16x8 pa0 = *(const bf16x8*)&Pb[w][ 0 + l15][kf*32 + g4*8];
      bf16x8 pa1 = *(const bf16x8*)&Pb[w][16 + l15][kf*32 + g4*8];
#pragma unroll
      for (int nn=0;nn<6;nn++){
        bf16x8 vb = *(const bf16x8*)&Vs[nn*16 + l15][kf*32 + g4*8];
        acc[0][nn] = __builtin_amdgcn_mfma_f32_16x16x32_bf16(pa0, vb, acc[0][nn], 0,0,0);
        acc[1][nn] = __builtin_amdgcn_mfma_f32_16x16x32_bf16(pa1, vb, acc[1][nn], 0,0,0);
      }
    }
    __syncthreads();
  }

  if (g4 == 0){
    FAC[w*32 +  0 + l15] = 1.0f / l_run[0];
    FAC[w*32 + 16 + l15] = 1.0f / l_run[1];
  }
  float4 li0 = *(const float4*)&FAC[w*32 +  0 + g4*4];
  float4 li1 = *(const float4*)&FAC[w*32 + 16 + g4*4];
  float li[2][4] = {{li0.x,li0.y,li0.z,li0.w},{li1.x,li1.y,li1.z,li1.w}};
#pragma unroll
  for (int mo=0;mo<2;mo++)
#pragma unroll
    for (int nn=0;nn<6;nn++)
#pragma unroll
      for (int j=0;j<4;j++){
        int q = w*32 + mo*16 + g4*4 + j;
        int d = nn*16 + l15;
        attn[((long)(b*128+q))*1536 + h*96 + d] = f2bf(acc[mo][nn][j]*li[mo][j]);
      }
}

// ---------------------------------------------------------------------------
// 128x128 2-phase GEMM (verified r2) for preamble shapes.
// ---------------------------------------------------------------------------
template<int GELU, int BIAS, int RES, int OUTF32>
__global__ __launch_bounds__(256)
void gemm_t(const short* __restrict__ A, const short* __restrict__ B,
            void* __restrict__ C, const float* __restrict__ bias,
            const float* __restrict__ res,
            int K, int lda, int ldb, int ldc,
            int Mvalid, int NBmax, int Nwrite,
            int zdiv, long sA1, long sA2, long sB1, long sB2, long sC1, long sC2,
            float scale)
{
  __shared__ __align__(16) short As[2][128*32];
  __shared__ __align__(16) short Bs[2][128*32];

  int z = blockIdx.z;
  int zq = z / zdiv, zr = z - zq*zdiv;
  const short* Ab = A + zq*sA1 + zr*sA2;
  const short* Bb = B + zq*sB1 + zr*sB2;
  long cOff = zq*sC1 + zr*sC2;
  int m0 = blockIdx.y * 128;
  int n0 = blockIdx.x * 128;
  int tid = threadIdx.x;
  int lane = tid & 63;
  int w = tid >> 6;
  int wm = (w >> 1) * 64, wn = (w & 1) * 64;

  int sr = lane >> 2;
  int sc = (lane & 3) * 8;
  int ar0 = m0 + w*32 + sr;
  int br0 = n0 + w*32 + sr;

  int raA0 = ar0;      if (raA0 > Mvalid-1) raA0 = Mvalid-1;
  int raA1 = ar0 + 16; if (raA1 > Mvalid-1) raA1 = Mvalid-1;
  int rbB0 = br0;      if (rbB0 > NBmax-1) rbB0 = NBmax-1;
  int rbB1 = br0 + 16; if (rbB1 > NBmax-1) rbB1 = NBmax-1;
  const short* gA0 = Ab + (long)raA0*lda + sc;
  const short* gA1 = Ab + (long)raA1*lda + sc;
  const short* gB0 = Bb + (long)rbB0*ldb + sc;
  const short* gB1 = Bb + (long)rbB1*ldb + sc;
  int ldsRow0 = (w*32)*32;
  int ldsRow1 = (w*32 + 16)*32;

  f32x4 acc[4][4];
#pragma unroll
  for (int i=0;i<4;i++)
#pragma unroll
    for (int j=0;j<4;j++) acc[i][j] = (f32x4){0.f,0.f,0.f,0.f};

  auto stage = [&](int buf, int kb){
    __builtin_amdgcn_global_load_lds(
        (const __attribute__((address_space(1))) u32*)(gA0 + kb),
        (__attribute__((address_space(3))) u32*)(&As[buf][ldsRow0]), 16, 0, 0);
    __builtin_amdgcn_global_load_lds(
        (const __attribute__((address_space(1))) u32*)(gA1 + kb),
        (__attribute__((address_space(3))) u32*)(&As[buf][ldsRow1]), 16, 0, 0);
    __builtin_amdgcn_global_load_lds(
        (const __attribute__((address_space(1))) u32*)(gB0 + kb),
        (__attribute__((address_space(3))) u32*)(&Bs[buf][ldsRow0]), 16, 0, 0);
    __builtin_amdgcn_global_load_lds(
        (const __attribute__((address_space(1))) u32*)(gB1 + kb),
        (__attribute__((address_space(3))) u32*)(&Bs[buf][ldsRow1]), 16, 0, 0);
  };

  int nt = K >> 5;
  stage(0, 0);
  __syncthreads();

  int kq = (lane >> 4) * 8;
  int rsel = lane & 15;
  int cur = 0;
  for (int t = 0; t < nt; ++t){
    if (t + 1 < nt) stage(cur ^ 1, (t+1)*32);

    bf16x8 af[4], bfr[4];
#pragma unroll
    for (int m=0;m<4;m++) af[m]  = *(const bf16x8*)&As[cur][(wm + m*16 + rsel)*32 + kq];
#pragma unroll
    for (int n=0;n<4;n++) bfr[n] = *(const bf16x8*)&Bs[cur][(wn + n*16 + rsel)*32 + kq];
#pragma unroll
    for (int m=0;m<4;m++)
#pragma unroll
      for (int n=0;n<4;n++)
        acc[m][n] = __builtin_amdgcn_mfma_f32_16x16x32_bf16(af[m], bfr[n], acc[m][n], 0, 0, 0);

    __syncthreads();
    cur ^= 1;
  }

  int cq = (lane >> 4) * 4;
  int csel = lane & 15;
#pragma unroll
  for (int m=0;m<4;m++){
#pragma unroll
    for (int n=0;n<4;n++){
#pragma unroll
      for (int j=0;j<4;j++){
        int gm = m0 + wm + m*16 + cq + j;
        int gn = n0 + wn + n*16 + csel;
        if (gm < Mvalid && gn < Nwrite){
          float v = acc[m][n][j] * scale;
          if (BIAS) v += bias[gn];
          if (GELU) v = 0.5f*v*(1.0f + erff(v*0.70710678118654752f));
          long off = cOff + (long)gm*ldc + gn;
          if (OUTF32){
            float rv = RES ? res[off] : 0.0f;
            ((float*)C)[off] = v + rv;
          } else {
            ((short*)C)[off] = f2bf(v);
          }
        }
      }
    }
  }
}

// ---------------------------------------------------------------------------
__global__ __launch_bounds__(256)
void convT(const float* __restrict__ in, short* __restrict__ out,
           int K, int N, const float* __restrict__ s)
{
  __shared__ float tile[32][33];
  int kb = blockIdx.y*32, nb = blockIdx.x*32;
  int tx = threadIdx.x & 31, ty = threadIdx.x >> 5;
  for (int i = ty; i < 32; i += 8){
    int k = kb + i, n = nb + tx;
    float v = 0.f;
    if (k < K && n < N){ v = in[(long)k*N + n]; if (s) v *= s[k]; }
    tile[i][tx] = v;
  }
  __syncthreads();
  for (int i = ty; i < 32; i += 8){
    int n = nb + i, k = kb + tx;
    if (n < N && k < K) out[(long)n*K + k] = f2bf(tile[tx][i]);
  }
}

// merged per-layer Wq + Wkv(dual) transpose
__global__ __launch_bounds__(256)
void convT_qkv(const float* __restrict__ Wq, const float* __restrict__ Wkv,
               const float* __restrict__ s,
               short* __restrict__ outQ, short* __restrict__ outKx,
               short* __restrict__ outK)
{
  __shared__ float tile[32][33];
  __shared__ float sv[32];
  int b = blockIdx.x;
  int tx = threadIdx.x & 31, ty = threadIdx.x >> 5;
  if (b < 1728){
    int bx = b % 48, byy = b / 48;
    int kb = byy*32, nb = bx*32;
    for (int i = ty; i < 32; i += 8)
      tile[i][tx] = Wq[(long)(kb + i)*1536 + nb + tx];
    __syncthreads();
    for (int i = ty; i < 32; i += 8)
      outQ[(long)(nb + i)*1152 + kb + tx] = f2bf(tile[tx][i]);
  } else {
    int b2 = b - 1728;
    int bx = b2 % 96, byy = b2 / 96;
    int kb = byy*32, nb = bx*32;
    if (threadIdx.x < 32) sv[threadIdx.x] = s[kb + threadIdx.x];
    for (int i = ty; i < 32; i += 8)
      tile[i][tx] = Wkv[(long)(kb + i)*3072 + nb + tx];
    __syncthreads();
    for (int i = ty; i < 32; i += 8){
      float v = tile[tx][i];
      long o = (long)(nb + i)*1152 + kb + tx;
      outK[o]  = f2bf(v);
      outKx[o] = f2bf(v * sv[tx]);
    }
  }
}

// merged per-layer Wo + fw1 + fw2 transpose (one dispatch, 12096 blocks)
__global__ __launch_bounds__(256)
void convT_ffo(const float* __restrict__ Wo, const float* __restrict__ fw1,
               const float* __restrict__ fw2,
               short* __restrict__ outWo, short* __restrict__ outF1,
               short* __restrict__ outF2)
{
  __shared__ float tile[32][33];
  int b = blockIdx.x;
  int tx = threadIdx.x & 31, ty = threadIdx.x >> 5;
  const float* in; short* out; int K, N, kb, nb;
  if (b < 1728){
    in = Wo; out = outWo; K = 1536; N = 1152;
    nb = (b % 36)*32; kb = (b / 36)*32;
  } else if (b < 6912){
    int b2 = b - 1728;
    in = fw1; out = outF1; K = 1152; N = 4608;
    nb = (b2 % 144)*32; kb = (b2 / 144)*32;
  } else {
    int b3 = b - 6912;
    in = fw2; out = outF2; K = 4608; N = 1152;
    nb = (b3 % 36)*32; kb = (b3 / 36)*32;
  }
  for (int i = ty; i < 32; i += 8)
    tile[i][tx] = in[(long)(kb + i)*N + nb + tx];
  __syncthreads();
  for (int i = ty; i < 32; i += 8)
    out[(long)(nb + i)*K + kb + tx] = f2bf(tile[tx][i]);
}

// biasf[L][n] = sum_k nm_b[L][k] * Wkv[L][k*3072+n]  (all layers, one dispatch)
__global__ __launch_bounds__(256)
void biasfold6(const float* __restrict__ Wkv, const float* __restrict__ nm_b,
               float* __restrict__ outb)
{
  int L = blockIdx.y;
  int n = blockIdx.x*256 + threadIdx.x;
  const float* W = Wkv + (size_t)L*1152*3072;
  const float* bvec = nm_b + L*1152;
  float s = 0.f;
  for (int k=0;k<1152;k++) s += bvec[k]*W[(long)k*3072 + n];
  outb[L*3072 + n] = s;
}

__global__ __launch_bounds__(256)
void cvt_bf16x4(const float* __restrict__ in, short* __restrict__ o, long n)
{
  long i = ((long)blockIdx.x*256 + threadIdx.x)*4;
  if (i >= n) return;
  float4 v = *(const float4*)(in + i);
  short4 s4;
  s4.x = f2bf(v.x); s4.y = f2bf(v.y); s4.z = f2bf(v.z); s4.w = f2bf(v.w);
  *(short4*)&o[i] = s4;
}

__global__ __launch_bounds__(256)
void latcopy(const float* __restrict__ latents, float* __restrict__ lat)
{
  int idx = blockIdx.x*256 + threadIdx.x;
  int d = idx % 1152; int j = (idx / 1152) % 64; int b = idx / (1152*64);
  lat[((long)b*128 + j)*1152 + d] = latents[j*1152 + d];
}

template<int OUTF32>
__global__ __launch_bounds__(256)
void ln_k(const float* __restrict__ in, void* __restrict__ outp,
          const float* __restrict__ w, const float* __restrict__ b,
          int grpSel, int grpStride)
{
  const int D = 1152;
  int r = blockIdx.x;
  long ir = (long)(r / grpSel)*grpStride + (r % grpSel);
  const float* x = in + ir*D;
  int tid = threadIdx.x;
  float s1=0.f, s2=0.f;
  float xv[5];
#pragma unroll
  for (int t=0;t<5;t++){
    int i = tid + t*256;
    xv[t] = (i < D) ? x[i] : 0.f;
    s1 += xv[t]; s2 += xv[t]*xv[t];
  }
#pragma unroll
  for (int o=32;o;o>>=1){ s1 += __shfl_xor(s1,o); s2 += __shfl_xor(s2,o); }
  __shared__ float red[8];
  int wid = tid>>6, lane = tid&63;
  if (lane==0){ red[wid]=s1; red[4+wid]=s2; }
  __syncthreads();
  s1 = red[0]+red[1]+red[2]+red[3];
  s2 = red[4]+red[5]+red[6]+red[7];
  float mu = s1 / D;
  float var = s2 / D - mu*mu;
  float rs = rsqrtf(var + 1e-5f);
#pragma unroll
  for (int t=0;t<5;t++){
    int i = tid + t*256;
    if (i >= D) break;
    float v = (xv[t]-mu)*rs;
    if (w) v = v*w[i] + b[i];
    if (OUTF32) ((float*)outp)[(long)r*D + i] = v;
    else        ((short*)outp)[(long)r*D + i] = f2bf(v);
  }
}

// ---------------------------------------------------------------------------

extern "C" void kernel_launch(void* const* d_in, const int* in_sizes, int n_in,
                              void* d_out, int out_size, void* d_ws, size_t ws_size,
                              hipStream_t stream)
{
  const float* x      = (const float*)d_in[0];
  const float* tein   = (const float*)d_in[1];
  const float* lat0   = (const float*)d_in[2];
  const float* txt_w1 = (const float*)d_in[3];
  const float* txt_b1 = (const float*)d_in[4];
  const float* txt_w2 = (const float*)d_in[5];
  const float* txt_b2 = (const float*)d_in[6];
  const float* nm_w   = (const float*)d_in[7];
  const float* nm_b   = (const float*)d_in[8];
  const float* nl_w   = (const float*)d_in[9];
  const float* nl_b   = (const float*)d_in[10];
  const float* Wq     = (const float*)d_in[11];
  const float* Wkv    = (const float*)d_in[12];
  const float* Wo     = (const float*)d_in[13];
  const float* ffln_w = (const float*)d_in[14];
  const float* ffln_b = (const float*)d_in[15];
  const float* ff_w1  = (const float*)d_in[16];
  const float* ff_w2  = (const float*)d_in[17];
  const float* oln_w  = (const float*)d_in[18];
  const float* oln_b  = (const float*)d_in[19];
  float* out = (float*)d_out;
  (void)in_sizes; (void)n_in; (void)out_size; (void)ws_size;

  char* base = (char*)d_ws;
  size_t off = 0;
  auto alloc = [&](size_t bytes)->char*{
    char* r = base + off;
    off += (bytes + 255) & ~(size_t)255;
    return r;
  };
  short* wT    = (short*)alloc(4608ULL*1152*2);   // Wq^T | Wkv^T
  short* wTx   = (short*)alloc(3072ULL*1152*2);   // nm-scaled Wkv^T
  short* wTo   = (short*)alloc(1152ULL*1536*2);   // Wo^T
  short* wTf1  = (short*)alloc(4608ULL*1152*2);   // fw1^T
  short* wTf2  = (short*)alloc(1152ULL*4608*2);   // fw2^T
  float* biasf = (float*)alloc(6*3072*4);
  float* ppart = (float*)alloc(2ULL*4096*1152*4);
  short* xnorm = (short*)alloc(23328ULL*1152*2);
  float* lat   = (float*)alloc(4096ULL*1152*4);
  short* lm    = (short*)alloc(4096ULL*1152*2);
  short* qb    = (short*)alloc(4096ULL*1536*2);
  short* kv    = (short*)alloc(27424ULL*3072*2);
  short* SP    = (short*)alloc(2048ULL*4096*2 + 2048ULL*1152*2);
  short* attn  = (short*)alloc(4096ULL*1536*2);
  short* ffh   = (short*)alloc(4096ULL*4608*2);
  short* txtin = SP;
  short* txth  = SP + 2048ULL*4096;

  // ---- preamble ----
  cvt_bf16x4<<<8192,256,0,stream>>>(tein, txtin, 2048LL*4096);
  convT<<<dim3(36,128),256,0,stream>>>(txt_w1, wT, 4096, 1152, nullptr);
  gemm_t<1,1,0,0><<<dim3(9,16,1),256,0,stream>>>(txtin, wT, txth, txt_b1, nullptr,
      4096,4096,4096,1152, 2048,1152,1152, 1, 0,0,0,0,0,0, 1.f);
  convT<<<dim3(36,36),256,0,stream>>>(txt_w2, wT, 1152, 1152, nullptr);
  gemm_t<0,1,0,1><<<dim3(9,1,32),256,0,stream>>>(txth, wT, lat + 64*1152, txt_b2, nullptr,
      1152,1152,1152,1152, 64,1152,1152, 1, 64L*1152,0, 0,0, 128L*1152,0, 1.f);
  latcopy<<<9216,256,0,stream>>>(lat0, lat);

  ln_k<0><<<23328,256,0,stream>>>(x, xnorm, nullptr, nullptr, 1<<28, 0);
  ln_k<0><<<4096,256,0,stream>>>(lat, lm, nl_w, nl_b, 1<<28, 0);
  biasfold6<<<dim3(12,6),256,0,stream>>>(Wkv, nm_b, biasf);

  for (int L=0; L<6; L++){
    const float* WqL  = Wq    + (size_t)L*1152*1536;
    const float* WkvL = Wkv   + (size_t)L*1152*3072;
    const float* WoL  = Wo    + (size_t)L*1536*1152;
    const float* fw1  = ff_w1 + (size_t)L*1152*4608;
    const float* fw2  = ff_w2 + (size_t)L*4608*1152;
    int Ln = (L+1 < 6) ? (L+1) : 5;

    convT_qkv<<<5184,256,0,stream>>>(WqL, WkvL, nm_w + L*1152,
        wT, wTx, wT + 1536*1152);

    // merged q|kv + kvx (R22-verified correct & faster than the split pair)
    gemm_qkvx<<<2784,512,0,stream>>>(lm, xnorm, wT, wTx, qb, kv, biasf + L*3072);

    flash_attn<<<512,256,0,stream>>>(qb, kv, attn);

    convT_ffo<<<12096,256,0,stream>>>(WoL, fw1, fw2, wTo, wTf1, wTf2);

    gemm_v2<0,0,1,0,1><<<dim3(32,5,2),512,0,stream>>>(attn, wTo, ppart, nullptr, nullptr,
        768,1536,1536,1152, 4096, 1152, 1152);
    red2_ln<<<4096,256,0,stream>>>(lat, ppart, 4096L*1152, lm,
        ffln_w + L*1152, ffln_b + L*1152);

    gemm_v2<1,0,0,0,0><<<dim3(32,18),512,0,stream>>>(lm, wTf1, ffh, nullptr, nullptr,
        1152,1152,1152,4608, 4096, 4608, 4608);
    gemm_v2<0,0,1,0,1><<<dim3(32,5,2),512,0,stream>>>(ffh, wTf2, ppart, nullptr, nullptr,
        2304,4608,4608,1152, 4096, 1152, 1152);
    red2_ln<<<4096,256,0,stream>>>(lat, ppart, 4096L*1152, lm,
        (L+1 < 6) ? (nl_w + Ln*1152) : nullptr, nl_b + Ln*1152);
  }

  ln_k<1><<<2048,256,0,stream>>>(lat, out, oln_w, oln_b, 64, 128);
}

// Round 24
// 3590.336 us; speedup vs baseline: 1.0472x; 1.0113x over previous
//
#include <hip/hip_runtime.h>
#include <hip/hip_bf16.h>
#include <math.h>

// InstructPerceiverResampler on MI355X (gfx950).
// Round 24 (base = R23, 3631us): gemm_f2t = ff2-GEMM (320 blocks, was 62%
// machine fill) merged with NEXT layer's convT_qkv (5184 tile-blocks widened
// to 512 thr) — independent work backfills ff2's idle slots and convT_qkv
// leaves the critical path. Layer-0 convT_qkv moves to the preamble; L=5
// harmlessly recomputes its own transposes. Everything else = R23 (verified).

typedef __attribute__((ext_vector_type(4))) float f32x4;
typedef __attribute__((ext_vector_type(8))) short bf16x8;
typedef unsigned int u32;

#define DEV __device__ __forceinline__

DEV float bf2f(short s){ union{u32 u; float f;} v; v.u = ((u32)(unsigned short)s) << 16; return v.f; }
DEV short f2bf(float f){
  union{float f; u32 u;} v; v.f = f;
  u32 r = (v.u + 0x7FFFu + ((v.u >> 16) & 1u)) >> 16;
  return (short)r;
}

DEV u32 lds_off(const short* p){
  return (u32)(uintptr_t)(__attribute__((address_space(3))) const short*)p;
}
template<int OFF>
DEV bf16x8 dsro(u32 addr){
  bf16x8 r;
  asm volatile("ds_read_b128 %0, %1 offset:%2" : "=v"(r) : "v"(addr), "i"(OFF));
  return r;
}

// ---------------------------------------------------------------------------
// gemm_v2 (R21 verified): C[m,n] = A[m,k]*B[n,k] (+bias)(+gelu), 128x256.
// ---------------------------------------------------------------------------
template<int GELU, int BIAS, int OUTF32, int CMAP, int KSPLIT>
__global__ __launch_bounds__(512, 4)
void gemm_v2(const short* __restrict__ A, const short* __restrict__ Bm,
             void* __restrict__ Cv, short* __restrict__ C2,
             const float* __restrict__ bias,
             int K, int lda, int ldb, int ldc,
             int Mvalid, int NBmax, int Nwrite)
{
  __shared__ __align__(16) short LDS[36864];

  int Mb = gridDim.x;
  int nwg = gridDim.x * gridDim.y;
  int bid = blockIdx.y * gridDim.x + blockIdx.x;
  int m0, n0;
  if ((Mb & 7) == 0){
    int mslab = Mb >> 3;
    int c = bid & 7, s = bid >> 3;
    int ml = s % mslab, nl = s / mslab;
    m0 = (c*mslab + ml) * 128;
    n0 = nl * 256;
  } else if ((nwg & 7) == 0){
    int chunk = nwg >> 3;
    int b2 = (bid & 7)*chunk + (bid >> 3);
    int by = b2 / Mb;
    m0 = (b2 - by*Mb) * 128;
    n0 = by * 256;
  } else {
    m0 = blockIdx.x * 128;
    n0 = blockIdx.y * 256;
  }
  int kzoff = KSPLIT ? (int)blockIdx.z * K : 0;

  int tid = threadIdx.x, lane = tid & 63, w = tid >> 6;
  int wr = w >> 2, wc = w & 3;
  int rsel = lane & 15, g4 = lane >> 4;

  int sl = lane >> 3;
  int l  = (lane & 7) ^ sl;
  int lc = (l & 3) * 8;
  int lh = l >> 2;
  const short* gA;
  { int r = m0 + w*8 + sl + lh*64; if (r > Mvalid-1) r = Mvalid-1;
    gA = A + (long)r*lda + lc + kzoff; }
  const short* gB0;
  { int r = n0 + w*8 + sl + lh*128; if (r > NBmax-1) r = NBmax-1;
    gB0 = Bm + (long)r*ldb + lc + kzoff; }
  const short* gB1;
  { int r = n0 + 64 + w*8 + sl + lh*128; if (r > NBmax-1) r = NBmax-1;
    gB1 = Bm + (long)r*ldb + lc + kzoff; }
  char* dA  = (char*)LDS + w*1024;
  char* dB0 = (char*)LDS + 8192  + w*1024;
  char* dB1 = (char*)LDS + 16384 + w*1024;

#define GLDS(src, dst) __builtin_amdgcn_global_load_lds( \
      (const __attribute__((address_space(1))) u32*)(src), \
      (__attribute__((address_space(3))) u32*)(dst), 16, 0, 0)
#define STAGE(bo, tau) do { \
    int kb = (tau)*32; \
    GLDS(gA  + kb, dA  + (bo)); \
    GLDS(gB0 + kb, dB0 + (bo)); \
    GLDS(gB1 + kb, dB1 + (bo)); \
  } while(0)

  u32 base = lds_off(LDS);
  u32 aAddr = base + (u32)(rsel*128 + (((wr*4 + g4) ^ (rsel & 7))*16));
  u32 bAddr = base + 8192u
            + (u32)(((wc & 1)*64 + rsel)*128 + ((((wc >> 1)*4 + g4) ^ (rsel & 7))*16));

  int nt = K >> 5;

  f32x4 acc[4][4];
#pragma unroll
  for (int i=0;i<4;i++)
#pragma unroll
    for (int j=0;j<4;j++) acc[i][j] = (f32x4){0.f,0.f,0.f,0.f};

  STAGE(0u, 0);
  if (nt > 1) STAGE(24576u, 1);

  u32 boCur = 0;
#pragma unroll 1
  for (int t=0; t<nt; ++t){
    if (t == nt-1) { asm volatile("s_waitcnt vmcnt(0)" ::: "memory"); }
    else           { asm volatile("s_waitcnt vmcnt(3)" ::: "memory"); }
    asm volatile("s_barrier" ::: "memory");
    u32 aa = aAddr + boCur, bb = bAddr + boCur;
    bf16x8 af[4], bfr[4];
    af[0]  = dsro<0>(aa);    af[1]  = dsro<2048>(aa);
    af[2]  = dsro<4096>(aa); af[3]  = dsro<6144>(aa);
    bfr[0] = dsro<0>(bb);    bfr[1] = dsro<2048>(bb);
    bfr[2] = dsro<4096>(bb); bfr[3] = dsro<6144>(bb);
    if (t+2 < nt){
      u32 boN2 = boCur + 49152u; if (boN2 >= 73728u) boN2 -= 73728u;
      STAGE(boN2, t+2);
    }
    asm volatile("s_waitcnt lgkmcnt(0)" ::: "memory");
    __builtin_amdgcn_sched_barrier(0);
    __builtin_amdgcn_s_setprio(1);
#pragma unroll
    for (int mi=0; mi<4; mi++)
#pragma unroll
      for (int nn=0; nn<4; nn++)
        acc[mi][nn] = __builtin_amdgcn_mfma_f32_16x16x32_bf16(af[mi], bfr[nn], acc[mi][nn], 0, 0, 0);
    __builtin_amdgcn_s_setprio(0);
    boCur += 24576u; if (boCur == 73728u) boCur = 0;
  }
#undef STAGE
#undef GLDS

  int cq = g4 * 4;
  int csel = rsel;
#pragma unroll
  for (int mi=0; mi<4; mi++){
#pragma unroll
    for (int nn=0; nn<4; nn++){
#pragma unroll
      for (int j=0; j<4; j++){
        int gm = m0 + wr*64 + mi*16 + cq + j;
        int gn = n0 + wc*64 + nn*16 + csel;
        if (gm < Mvalid && gn < Nwrite){
          float v = acc[mi][nn][j];
          if (BIAS) v += bias[gn];
          if (GELU) v = 0.5f*v*(1.0f + erff(v*0.70710678118654752f));
          if (CMAP == 0){
            long off = (long)gm*ldc + gn;
            if (KSPLIT) off += (long)blockIdx.z * ((long)Mvalid * ldc);
            if (OUTF32) ((float*)Cv)[off] = v;
            else        ((short*)Cv)[off] = f2bf(v);
          } else if (CMAP == 1){
            int bb2 = gm / 729;
            int jj = gm - bb2*729;
            ((short*)Cv)[((long)bb2*857 + jj)*3072 + gn] = f2bf(v);
          } else {
            if (gn < 1536){
              ((short*)Cv)[(long)gm*1536 + gn] = f2bf(v * 0.1020620726159657f);
            } else {
              int bb2 = gm >> 7, jj = gm & 127;
              C2[((long)bb2*857 + 729 + jj)*3072 + (gn - 1536)] = f2bf(v);
            }
          }
        }
      }
    }
  }
}

// ---------------------------------------------------------------------------
// gemm_qkvx (R22/R23 verified): blocks [0,576) = q|kv, [576,2784) = kvx.
// ---------------------------------------------------------------------------
__global__ __launch_bounds__(512, 4)
void gemm_qkvx(const short* __restrict__ lm, const short* __restrict__ xnorm,
               const short* __restrict__ wTq, const short* __restrict__ wTx,
               short* __restrict__ qb, short* __restrict__ kv,
               const float* __restrict__ biasL)
{
  __shared__ __align__(16) short LDS[36864];

  int bid = blockIdx.x;
  int which = (bid >= 576);
  const short* A; const short* Bm;
  int m0, n0, Mvalid, NBmax;
  if (!which){
    int mslab = 4;
    int c = bid & 7, s = bid >> 3;
    m0 = (c*mslab + s % mslab) * 128;
    n0 = (s / mslab) * 256;
    A = lm; Bm = wTq; Mvalid = 4096; NBmax = 4608;
  } else {
    int local = bid - 576;
    int mslab = 23;
    int c = local & 7, s = local >> 3;
    m0 = (c*mslab + s % mslab) * 128;
    n0 = (s / mslab) * 256;
    A = xnorm; Bm = wTx; Mvalid = 23328; NBmax = 3072;
  }

  int tid = threadIdx.x, lane = tid & 63, w = tid >> 6;
  int wr = w >> 2, wc = w & 3;
  int rsel = lane & 15, g4 = lane >> 4;

  int sl = lane >> 3;
  int l  = (lane & 7) ^ sl;
  int lc = (l & 3) * 8;
  int lh = l >> 2;
  const short* gA;
  { int r = m0 + w*8 + sl + lh*64; if (r > Mvalid-1) r = Mvalid-1;
    gA = A + (long)r*1152 + lc; }
  const short* gB0;
  { int r = n0 + w*8 + sl + lh*128; if (r > NBmax-1) r = NBmax-1;
    gB0 = Bm + (long)r*1152 + lc; }
  const short* gB1;
  { int r = n0 + 64 + w*8 + sl + lh*128; if (r > NBmax-1) r = NBmax-1;
    gB1 = Bm + (long)r*1152 + lc; }
  char* dA  = (char*)LDS + w*1024;
  char* dB0 = (char*)LDS + 8192  + w*1024;
  char* dB1 = (char*)LDS + 16384 + w*1024;

#define GLDS(src, dst) __builtin_amdgcn_global_load_lds( \
      (const __attribute__((address_space(1))) u32*)(src), \
      (__attribute__((address_space(3))) u32*)(dst), 16, 0, 0)
#define STAGE(bo, tau) do { \
    int kb = (tau)*32; \
    GLDS(gA  + kb, dA  + (bo)); \
    GLDS(gB0 + kb, dB0 + (bo)); \
    GLDS(gB1 + kb, dB1 + (bo)); \
  } while(0)

  u32 base = lds_off(LDS);
  u32 aAddr = base + (u32)(rsel*128 + (((wr*4 + g4) ^ (rsel & 7))*16));
  u32 bAddr = base + 8192u
            + (u32)(((wc & 1)*64 + rsel)*128 + ((((wc >> 1)*4 + g4) ^ (rsel & 7))*16));

  const int nt = 36;

  f32x4 acc[4][4];
#pragma unroll
  for (int i=0;i<4;i++)
#pragma unroll
    for (int j=0;j<4;j++) acc[i][j] = (f32x4){0.f,0.f,0.f,0.f};

  STAGE(0u, 0);
  STAGE(24576u, 1);

  u32 boCur = 0;
#pragma unroll 1
  for (int t=0; t<nt; ++t){
    if (t == nt-1) { asm volatile("s_waitcnt vmcnt(0)" ::: "memory"); }
    else           { asm volatile("s_waitcnt vmcnt(3)" ::: "memory"); }
    asm volatile("s_barrier" ::: "memory");
    u32 aa = aAddr + boCur, bb = bAddr + boCur;
    bf16x8 af[4], bfr[4];
    af[0]  = dsro<0>(aa);    af[1]  = dsro<2048>(aa);
    af[2]  = dsro<4096>(aa); af[3]  = dsro<6144>(aa);
    bfr[0] = dsro<0>(bb);    bfr[1] = dsro<2048>(bb);
    bfr[2] = dsro<4096>(bb); bfr[3] = dsro<6144>(bb);
    if (t+2 < nt){
      u32 boN2 = boCur + 49152u; if (boN2 >= 73728u) boN2 -= 73728u;
      STAGE(boN2, t+2);
    }
    asm volatile("s_waitcnt lgkmcnt(0)" ::: "memory");
    __builtin_amdgcn_sched_barrier(0);
    __builtin_amdgcn_s_setprio(1);
#pragma unroll
    for (int mi=0; mi<4; mi++)
#pragma unroll
      for (int nn=0; nn<4; nn++)
        acc[mi][nn] = __builtin_amdgcn_mfma_f32_16x16x32_bf16(af[mi], bfr[nn], acc[mi][nn], 0, 0, 0);
    __builtin_amdgcn_s_setprio(0);
    boCur += 24576u; if (boCur == 73728u) boCur = 0;
  }
#undef STAGE
#undef GLDS

  int cq = g4 * 4;
  int csel = rsel;
#pragma unroll
  for (int mi=0; mi<4; mi++){
#pragma unroll
    for (int nn=0; nn<4; nn++){
#pragma unroll
      for (int j=0; j<4; j++){
        int gm = m0 + wr*64 + mi*16 + cq + j;
        int gn = n0 + wc*64 + nn*16 + csel;
        if (!which){
          if (gm < 4096 && gn < 4608){
            float v = acc[mi][nn][j];
            if (gn < 1536){
              qb[(long)gm*1536 + gn] = f2bf(v * 0.1020620726159657f);
            } else {
              int bb2 = gm >> 7, jj = gm & 127;
              kv[((long)bb2*857 + 729 + jj)*3072 + (gn - 1536)] = f2bf(v);
            }
          }
        } else {
          if (gm < 23328 && gn < 3072){
            float v = acc[mi][nn][j] + biasL[gn];
            int bb2 = gm / 729;
            int jj = gm - bb2*729;
            kv[((long)bb2*857 + jj)*3072 + gn] = f2bf(v);
          }
        }
      }
    }
  }
}

// ---------------------------------------------------------------------------
// gemm_f2t: blocks [0,320) = ff2 split-K GEMM (exact R23 mapping);
// blocks [320,5504) = next-layer convT_qkv body (512 threads/tile).
// ---------------------------------------------------------------------------
__global__ __launch_bounds__(512, 4)
void gemm_f2t(const short* __restrict__ ffh, const short* __restrict__ wTf2,
              float* __restrict__ ppart,
              const float* __restrict__ WqN, const float* __restrict__ WkvN,
              const float* __restrict__ sN,
              short* __restrict__ outQ, short* __restrict__ outKx,
              short* __restrict__ outK)
{
  __shared__ __align__(16) short LDS[36864];
  __shared__ float tile[32][33];
  __shared__ float sv[32];

  int bid = blockIdx.x;
  if (bid >= 320){
    // ---- convT_qkv body, 512 threads per 32x32 tile ----
    int b = bid - 320;                   // 0..5183
    int tx = threadIdx.x & 31, ty = threadIdx.x >> 5;   // ty 0..15
    if (b < 1728){
      int bx = b % 48, byy = b / 48;     // Wq: K=1152, N=1536
      int kb = byy*32, nb = bx*32;
      for (int i = ty; i < 32; i += 16)
        tile[i][tx] = WqN[(long)(kb + i)*1536 + nb + tx];
      __syncthreads();
      for (int i = ty; i < 32; i += 16)
        outQ[(long)(nb + i)*1152 + kb + tx] = f2bf(tile[tx][i]);
    } else {
      int b2 = b - 1728;
      int bx = b2 % 96, byy = b2 / 96;   // Wkv dual: K=1152, N=3072
      int kb = byy*32, nb = bx*32;
      if (threadIdx.x < 32) sv[threadIdx.x] = sN[kb + threadIdx.x];
      for (int i = ty; i < 32; i += 16)
        tile[i][tx] = WkvN[(long)(kb + i)*3072 + nb + tx];
      __syncthreads();
      for (int i = ty; i < 32; i += 16){
        float v = tile[tx][i];
        long o = (long)(nb + i)*1152 + kb + tx;
        outK[o]  = f2bf(v);
        outKx[o] = f2bf(v * sv[tx]);
      }
    }
    return;
  }

  // ---- ff2 GEMM: K=2304/chunk, lda=ldb=4608, ldc=1152, Mvalid=4096 ----
  int bz  = bid / 160;                   // split-K chunk
  int lin = bid - bz*160;                // = by*32 + bx
  int c = lin & 7, s = lin >> 3;
  int m0 = (c*4 + (s & 3)) * 128;        // mslab=4 (Mb=32)
  int n0 = (s >> 2) * 256;
  int kzoff = bz * 2304;

  int tid = threadIdx.x, lane = tid & 63, w = tid >> 6;
  int wr = w >> 2, wc = w & 3;
  int rsel = lane & 15, g4 = lane >> 4;

  int sl = lane >> 3;
  int l  = (lane & 7) ^ sl;
  int lc = (l & 3) * 8;
  int lh = l >> 2;
  const short* gA;
  { int r = m0 + w*8 + sl + lh*64; if (r > 4095) r = 4095;
    gA = ffh + (long)r*4608 + lc + kzoff; }
  const short* gB0;
  { int r = n0 + w*8 + sl + lh*128; if (r > 1151) r = 1151;
    gB0 = wTf2 + (long)r*4608 + lc + kzoff; }
  const short* gB1;
  { int r = n0 + 64 + w*8 + sl + lh*128; if (r > 1151) r = 1151;
    gB1 = wTf2 + (long)r*4608 + lc + kzoff; }
  char* dA  = (char*)LDS + w*1024;
  char* dB0 = (char*)LDS + 8192  + w*1024;
  char* dB1 = (char*)LDS + 16384 + w*1024;

#define GLDS(src, dst) __builtin_amdgcn_global_load_lds( \
      (const __attribute__((address_space(1))) u32*)(src), \
      (__attribute__((address_space(3))) u32*)(dst), 16, 0, 0)
#define STAGE(bo, tau) do { \
    int kb = (tau)*32; \
    GLDS(gA  + kb, dA  + (bo)); \
    GLDS(gB0 + kb, dB0 + (bo)); \
    GLDS(gB1 + kb, dB1 + (bo)); \
  } while(0)

  u32 base = lds_off(LDS);
  u32 aAddr = base + (u32)(rsel*128 + (((wr*4 + g4) ^ (rsel & 7))*16));
  u32 bAddr = base + 8192u
            + (u32)(((wc & 1)*64 + rsel)*128 + ((((wc >> 1)*4 + g4) ^ (rsel & 7))*16));

  const int nt = 72;                     // 2304/32

  f32x4 acc[4][4];
#pragma unroll
  for (int i=0;i<4;i++)
#pragma unroll
    for (int j=0;j<4;j++) acc[i][j] = (f32x4){0.f,0.f,0.f,0.f};

  STAGE(0u, 0);
  STAGE(24576u, 1);

  u32 boCur = 0;
#pragma unroll 1
  for (int t=0; t<nt; ++t){
    if (t == nt-1) { asm volatile("s_waitcnt vmcnt(0)" ::: "memory"); }
    else           { asm volatile("s_waitcnt vmcnt(3)" ::: "memory"); }
    asm volatile("s_barrier" ::: "memory");
    u32 aa = aAddr + boCur, bb = bAddr + boCur;
    bf16x8 af[4], bfr[4];
    af[0]  = dsro<0>(aa);    af[1]  = dsro<2048>(aa);
    af[2]  = dsro<4096>(aa); af[3]  = dsro<6144>(aa);
    bfr[0] = dsro<0>(bb);    bfr[1] = dsro<2048>(bb);
    bfr[2] = dsro<4096>(bb); bfr[3] = dsro<6144>(bb);
    if (t+2 < nt){
      u32 boN2 = boCur + 49152u; if (boN2 >= 73728u) boN2 -= 73728u;
      STAGE(boN2, t+2);
    }
    asm volatile("s_waitcnt lgkmcnt(0)" ::: "memory");
    __builtin_amdgcn_sched_barrier(0);
    __builtin_amdgcn_s_setprio(1);
#pragma unroll
    for (int mi=0; mi<4; mi++)
#pragma unroll
      for (int nn=0; nn<4; nn++)
        acc[mi][nn] = __builtin_amdgcn_mfma_f32_16x16x32_bf16(af[mi], bfr[nn], acc[mi][nn], 0, 0, 0);
    __builtin_amdgcn_s_setprio(0);
    boCur += 24576u; if (boCur == 73728u) boCur = 0;
  }
#undef STAGE
#undef GLDS

  int cq = g4 * 4;
  int csel = rsel;
  long zoff = (long)bz * (4096L*1152);
#pragma unroll
  for (int mi=0; mi<4; mi++){
#pragma unroll
    for (int nn=0; nn<4; nn++){
#pragma unroll
      for (int j=0; j<4; j++){
        int gm = m0 + wr*64 + mi*16 + cq + j;
        int gn = n0 + wc*64 + nn*16 + csel;
        if (gm < 4096 && gn < 1152){
          ppart[zoff + (long)gm*1152 + gn] = acc[mi][nn][j];
        }
      }
    }
  }
}

// ---------------------------------------------------------------------------
// red2_ln: lat[r] += p0[r] + p1[r], then (if w) lm[r] = LN(lat[r]; w,b).
// ---------------------------------------------------------------------------
__global__ __launch_bounds__(256)
void red2_ln(float* __restrict__ lat, const float* __restrict__ p, long n,
             short* __restrict__ lm, const float* __restrict__ w,
             const float* __restrict__ b)
{
  const int D = 1152;
  int r = blockIdx.x;
  long rb = (long)r*D;
  int tid = threadIdx.x;
  float s1=0.f, s2=0.f;
  float xv[5];
#pragma unroll
  for (int t=0;t<5;t++){
    int i = tid + t*256;
    float v = 0.f;
    if (i < D){
      v = lat[rb+i] + p[rb+i] + p[n+rb+i];
      lat[rb+i] = v;
    }
    xv[t] = v; s1 += v; s2 += v*v;
  }
  if (!w) return;
#pragma unroll
  for (int o=32;o;o>>=1){ s1 += __shfl_xor(s1,o); s2 += __shfl_xor(s2,o); }
  __shared__ float red[8];
  int wid = tid>>6, lane = tid&63;
  if (lane==0){ red[wid]=s1; red[4+wid]=s2; }
  __syncthreads();
  s1 = red[0]+red[1]+red[2]+red[3];
  s2 = red[4]+red[5]+red[6]+red[7];
  float mu = s1 / D;
  float var = s2 / D - mu*mu;
  float rs = rsqrtf(var + 1e-5f);
#pragma unroll
  for (int t=0;t<5;t++){
    int i = tid + t*256;
    if (i >= D) break;
    lm[rb+i] = f2bf((xv[t]-mu)*rs*w[i] + b[i]);
  }
}

// ---------------------------------------------------------------------------
// Flash attention with fused V-transpose (R19, verified).
// ---------------------------------------------------------------------------
__global__ __launch_bounds__(256)
void flash_attn(const short* __restrict__ qb, const short* __restrict__ kv,
                short* __restrict__ attn)
{
  __shared__ short Kt[96][104];
  __shared__ short Vs[96][104];
  __shared__ short Pb[4][32][104];
  __shared__ float FAC[128];

  int z = blockIdx.x;
  int b = z >> 4, h = z & 15;
  int tid = threadIdx.x;
  int lane = tid & 63;
  int w = tid >> 6;
  int l15 = lane & 15, g4 = lane >> 4;

  bf16x8 qf[2][3];
#pragma unroll
  for (int n=0;n<2;n++)
#pragma unroll
    for (int kf=0;kf<3;kf++)
      qf[n][kf] = *(const bf16x8*)&qb[((long)(b*128 + w*32 + n*16 + l15))*1536
                                     + h*96 + kf*32 + g4*8];

  f32x4 acc[2][6];
#pragma unroll
  for (int i=0;i<2;i++)
#pragma unroll
    for (int j=0;j<6;j++) acc[i][j] = (f32x4){0.f,0.f,0.f,0.f};
  float m_run[2] = {-1e30f, -1e30f};
  float l_run[2] = {0.f, 0.f};

  const short* kvb = kv + (long)b*857*3072 + h*96;
  const short* vvb = kvb + 1536;

  for (int t=0; t<9; ++t){
    int k0 = t*96;
    for (int c = tid; c < 1152; c += 256){
      int r = c / 12;
      int c12 = c - r*12;
      int key = k0 + r; if (key > 856) key = 856;
      *(bf16x8*)&Kt[r][c12*8] = *(const bf16x8*)&kvb[(long)key*3072 + c12*8];
      bf16x8 vv = *(const bf16x8*)&vvb[(long)key*3072 + c12*8];
#pragma unroll
      for (int j=0;j<8;j++) Vs[c12*8 + j][r] = ((short*)&vv)[j];
    }
    __syncthreads();

    f32x4 st[6][2];
#pragma unroll
    for (int m=0;m<6;m++){ st[m][0]=(f32x4){0,0,0,0}; st[m][1]=(f32x4){0,0,0,0}; }
#pragma unroll
    for (int kf=0;kf<3;kf++){
      bf16x8 af[6];
#pragma unroll
      for (int m=0;m<6;m++) af[m] = *(const bf16x8*)&Kt[m*16 + l15][kf*32 + g4*8];
#pragma unroll
      for (int m=0;m<6;m++){
        st[m][0] = __builtin_amdgcn_mfma_f32_16x16x32_bf16(af[m], qf[0][kf], st[m][0], 0,0,0);
        st[m][1] = __builtin_amdgcn_mfma_f32_16x16x32_bf16(af[m], qf[1][kf], st[m][1], 0,0,0);
      }
    }

    if (k0 + 96 > 857){
#pragma unroll
      for (int m=0;m<6;m++)
#pragma unroll
        for (int j=0;j<4;j++){
          if (k0 + m*16 + g4*4 + j > 856){ st[m][0][j] = -1e30f; st[m][1][j] = -1e30f; }
        }
    }

#pragma unroll
    for (int n=0;n<2;n++){
      float mx = -1e30f;
#pragma unroll
      for (int m=0;m<6;m++)
#pragma unroll
        for (int j=0;j<4;j++) mx = fmaxf(mx, st[m][n][j]);
      mx = fmaxf(mx, __shfl_xor(mx, 16));
      mx = fmaxf(mx, __shfl_xor(mx, 32));
      float mn = fmaxf(m_run[n], mx);
      float f  = __expf(m_run[n] - mn);
      m_run[n] = mn;
      float s = 0.f;
#pragma unroll
      for (int m=0;m<6;m++)
#pragma unroll
        for (int j=0;j<4;j++){
          float e = __expf(st[m][n][j] - mn);
          st[m][n][j] = e; s += e;
        }
      s += __shfl_xor(s, 16);
      s += __shfl_xor(s, 32);
      l_run[n] = l_run[n]*f + s;
      if (g4 == 0) FAC[w*32 + n*16 + l15] = f;
    }

#pragma unroll
    for (int m=0;m<6;m++)
#pragma unroll
      for (int n=0;n<2;n++){
        short4 pk;
        pk.x = f2bf(st[m][n][0]); pk.y = f2bf(st[m][n][1]);
        pk.z = f2bf(st[m][n][2]); pk.w = f2bf(st[m][n][3]);
        *(short4*)&Pb[w][n*16 + l15][m*16 + g4*4] = pk;
      }

    {
      float4 fj0 = *(const float4*)&FAC[w*32 +  0 + g4*4];
      float4 fj1 = *(const float4*)&FAC[w*32 + 16 + g4*4];
#pragma unroll
      for (int nn=0;nn<6;nn++){
        acc[0][nn][0] *= fj0.x; acc[0][nn][1] *= fj0.y;
        acc[0][nn][2] *= fj0.z; acc[0][nn][3] *= fj0.w;
        acc[1][nn][0] *= fj1.x; acc[1][nn][1] *= fj1.y;
        acc[1][nn][2] *= fj1.z; acc[1][nn][3] *= fj1.w;
      }
    }

#pragma unroll
    for (int kf=0;kf<3;kf++){
      bf16x8 pa0 = *(const bf16x8*)&Pb[w][ 0 + l15][kf*32 + g4*8];
      bf16x8 pa1 = *(const bf16x8*)&Pb[w][16 + l15][kf*32 + g4*8];
#pragma unroll
      for (int nn=0;nn<6;nn++){
        bf16x8 vb = *(const bf16x8*)&Vs[nn*16 + l15][kf*32 + g4*8];
        acc[0][nn] = __builtin_amdgcn_mfma_f32_16x16x32_bf16(pa0, vb, acc[0][nn], 0,0,0);
        acc[1][nn] = __builtin_amdgcn_mfma_f32_16x16x32_bf16(pa1, vb, acc[1][nn], 0,0,0);
      }
    }
    __syncthreads();
  }

  if (g4 == 0){
    FAC[w*32 +  0 + l15] = 1.0f / l_run[0];
    FAC[w*32 + 16 + l15] = 1.0f / l_run[1];
  }
  float4 li0 = *(const float4*)&FAC[w*32 +  0 + g4*4];
  float4 li1 = *(const float4*)&FAC[w*32 + 16 + g4*4];
  float li[2][4] = {{li0.x,li0.y,li0.z,li0.w},{li1.x,li1.y,li1.z,li1.w}};
#pragma unroll
  for (int mo=0;mo<2;mo++)
#pragma unroll
    for (int nn=0;nn<6;nn++)
#pragma unroll
      for (int j=0;j<4;j++){
        int q = w*32 + mo*16 + g4*4 + j;
        int d = nn*16 + l15;
        attn[((long)(b*128+q))*1536 + h*96 + d] = f2bf(acc[mo][nn][j]*li[mo][j]);
      }
}

// ---------------------------------------------------------------------------
// 128x128 2-phase GEMM (verified r2) for preamble shapes.
// ---------------------------------------------------------------------------
template<int GELU, int BIAS, int RES, int OUTF32>
__global__ __launch_bounds__(256)
void gemm_t(const short* __restrict__ A, const short* __restrict__ B,
            void* __restrict__ C, const float* __restrict__ bias,
            const float* __restrict__ res,
            int K, int lda, int ldb, int ldc,
            int Mvalid, int NBmax, int Nwrite,
            int zdiv, long sA1, long sA2, long sB1, long sB2, long sC1, long sC2,
            float scale)
{
  __shared__ __align__(16) short As[2][128*32];
  __shared__ __align__(16) short Bs[2][128*32];

  int z = blockIdx.z;
  int zq = z / zdiv, zr = z - zq*zdiv;
  const short* Ab = A + zq*sA1 + zr*sA2;
  const short* Bb = B + zq*sB1 + zr*sB2;
  long cOff = zq*sC1 + zr*sC2;
  int m0 = blockIdx.y * 128;
  int n0 = blockIdx.x * 128;
  int tid = threadIdx.x;
  int lane = tid & 63;
  int w = tid >> 6;
  int wm = (w >> 1) * 64, wn = (w & 1) * 64;

  int sr = lane >> 2;
  int sc = (lane & 3) * 8;
  int ar0 = m0 + w*32 + sr;
  int br0 = n0 + w*32 + sr;

  int raA0 = ar0;      if (raA0 > Mvalid-1) raA0 = Mvalid-1;
  int raA1 = ar0 + 16; if (raA1 > Mvalid-1) raA1 = Mvalid-1;
  int rbB0 = br0;      if (rbB0 > NBmax-1) rbB0 = NBmax-1;
  int rbB1 = br0 + 16; if (rbB1 > NBmax-1) rbB1 = NBmax-1;
  const short* gA0 = Ab + (long)raA0*lda + sc;
  const short* gA1 = Ab + (long)raA1*lda + sc;
  const short* gB0 = Bb + (long)rbB0*ldb + sc;
  const short* gB1 = Bb + (long)rbB1*ldb + sc;
  int ldsRow0 = (w*32)*32;
  int ldsRow1 = (w*32 + 16)*32;

  f32x4 acc[4][4];
#pragma unroll
  for (int i=0;i<4;i++)
#pragma unroll
    for (int j=0;j<4;j++) acc[i][j] = (f32x4){0.f,0.f,0.f,0.f};

  auto stage = [&](int buf, int kb){
    __builtin_amdgcn_global_load_lds(
        (const __attribute__((address_space(1))) u32*)(gA0 + kb),
        (__attribute__((address_space(3))) u32*)(&As[buf][ldsRow0]), 16, 0, 0);
    __builtin_amdgcn_global_load_lds(
        (const __attribute__((address_space(1))) u32*)(gA1 + kb),
        (__attribute__((address_space(3))) u32*)(&As[buf][ldsRow1]), 16, 0, 0);
    __builtin_amdgcn_global_load_lds(
        (const __attribute__((address_space(1))) u32*)(gB0 + kb),
        (__attribute__((address_space(3))) u32*)(&Bs[buf][ldsRow0]), 16, 0, 0);
    __builtin_amdgcn_global_load_lds(
        (const __attribute__((address_space(1))) u32*)(gB1 + kb),
        (__attribute__((address_space(3))) u32*)(&Bs[buf][ldsRow1]), 16, 0, 0);
  };

  int nt = K >> 5;
  stage(0, 0);
  __syncthreads();

  int kq = (lane >> 4) * 8;
  int rsel = lane & 15;
  int cur = 0;
  for (int t = 0; t < nt; ++t){
    if (t + 1 < nt) stage(cur ^ 1, (t+1)*32);

    bf16x8 af[4], bfr[4];
#pragma unroll
    for (int m=0;m<4;m++) af[m]  = *(const bf16x8*)&As[cur][(wm + m*16 + rsel)*32 + kq];
#pragma unroll
    for (int n=0;n<4;n++) bfr[n] = *(const bf16x8*)&Bs[cur][(wn + n*16 + rsel)*32 + kq];
#pragma unroll
    for (int m=0;m<4;m++)
#pragma unroll
      for (int n=0;n<4;n++)
        acc[m][n] = __builtin_amdgcn_mfma_f32_16x16x32_bf16(af[m], bfr[n], acc[m][n], 0, 0, 0);

    __syncthreads();
    cur ^= 1;
  }

  int cq = (lane >> 4) * 4;
  int csel = lane & 15;
#pragma unroll
  for (int m=0;m<4;m++){
#pragma unroll
    for (int n=0;n<4;n++){
#pragma unroll
      for (int j=0;j<4;j++){
        int gm = m0 + wm + m*16 + cq + j;
        int gn = n0 + wn + n*16 + csel;
        if (gm < Mvalid && gn < Nwrite){
          float v = acc[m][n][j] * scale;
          if (BIAS) v += bias[gn];
          if (GELU) v = 0.5f*v*(1.0f + erff(v*0.70710678118654752f));
          long off = cOff + (long)gm*ldc + gn;
          if (OUTF32){
            float rv = RES ? res[off] : 0.0f;
            ((float*)C)[off] = v + rv;
          } else {
            ((short*)C)[off] = f2bf(v);
          }
        }
      }
    }
  }
}

// ---------------------------------------------------------------------------
__global__ __launch_bounds__(256)
void convT(const float* __restrict__ in, short* __restrict__ out,
           int K, int N, const float* __restrict__ s)
{
  __shared__ float tile[32][33];
  int kb = blockIdx.y*32, nb = blockIdx.x*32;
  int tx = threadIdx.x & 31, ty = threadIdx.x >> 5;
  for (int i = ty; i < 32; i += 8){
    int k = kb + i, n = nb + tx;
    float v = 0.f;
    if (k < K && n < N){ v = in[(long)k*N + n]; if (s) v *= s[k]; }
    tile[i][tx] = v;
  }
  __syncthreads();
  for (int i = ty; i < 32; i += 8){
    int n = nb + i, k = kb + tx;
    if (n < N && k < K) out[(long)n*K + k] = f2bf(tile[tx][i]);
  }
}

// merged per-layer Wq + Wkv(dual) transpose (preamble L0 only)
__global__ __launch_bounds__(256)
void convT_qkv(const float* __restrict__ Wq, const float* __restrict__ Wkv,
               const float* __restrict__ s,
               short* __restrict__ outQ, short* __restrict__ outKx,
               short* __restrict__ outK)
{
  __shared__ float tile[32][33];
  __shared__ float sv[32];
  int b = blockIdx.x;
  int tx = threadIdx.x & 31, ty = threadIdx.x >> 5;
  if (b < 1728){
    int bx = b % 48, byy = b / 48;
    int kb = byy*32, nb = bx*32;
    for (int i = ty; i < 32; i += 8)
      tile[i][tx] = Wq[(long)(kb + i)*1536 + nb + tx];
    __syncthreads();
    for (int i = ty; i < 32; i += 8)
      outQ[(long)(nb + i)*1152 + kb + tx] = f2bf(tile[tx][i]);
  } else {
    int b2 = b - 1728;
    int bx = b2 % 96, byy = b2 / 96;
    int kb = byy*32, nb = bx*32;
    if (threadIdx.x < 32) sv[threadIdx.x] = s[kb + threadIdx.x];
    for (int i = ty; i < 32; i += 8)
      tile[i][tx] = Wkv[(long)(kb + i)*3072 + nb + tx];
    __syncthreads();
    for (int i = ty; i < 32; i += 8){
      float v = tile[tx][i];
      long o = (long)(nb + i)*1152 + kb + tx;
      outK[o]  = f2bf(v);
      outKx[o] = f2bf(v * sv[tx]);
    }
  }
}

// merged per-layer Wo + fw1 + fw2 transpose (one dispatch, 12096 blocks)
__global__ __launch_bounds__(256)
void convT_ffo(const float* __restrict__ Wo, const float* __restrict__ fw1,
               const float* __restrict__ fw2,
               short* __restrict__ outWo, short* __restrict__ outF1,
               short* __restrict__ outF2)
{
  __shared__ float tile[32][33];
  int b = blockIdx.x;
  int tx = threadIdx.x & 31, ty = threadIdx.x >> 5;
  const float* in; short* out; int K, N, kb, nb;
  if (b < 1728){
    in = Wo; out = outWo; K = 1536; N = 1152;
    nb = (b % 36)*32; kb = (b / 36)*32;
  } else if (b < 6912){
    int b2 = b - 1728;
    in = fw1; out = outF1; K = 1152; N = 4608;
    nb = (b2 % 144)*32; kb = (b2 / 144)*32;
  } else {
    int b3 = b - 6912;
    in = fw2; out = outF2; K = 4608; N = 1152;
    nb = (b3 % 36)*32; kb = (b3 / 36)*32;
  }
  for (int i = ty; i < 32; i += 8)
    tile[i][tx] = in[(long)(kb + i)*N + nb + tx];
  __syncthreads();
  for (int i = ty; i < 32; i += 8)
    out[(long)(nb + i)*K + kb + tx] = f2bf(tile[tx][i]);
}

// biasf[L][n] = sum_k nm_b[L][k] * Wkv[L][k*3072+n]  (all layers, one dispatch)
__global__ __launch_bounds__(256)
void biasfold6(const float* __restrict__ Wkv, const float* __restrict__ nm_b,
               float* __restrict__ outb)
{
  int L = blockIdx.y;
  int n = blockIdx.x*256 + threadIdx.x;
  const float* W = Wkv + (size_t)L*1152*3072;
  const float* bvec = nm_b + L*1152;
  float s = 0.f;
  for (int k=0;k<1152;k++) s += bvec[k]*W[(long)k*3072 + n];
  outb[L*3072 + n] = s;
}

__global__ __launch_bounds__(256)
void cvt_bf16x4(const float* __restrict__ in, short* __restrict__ o, long n)
{
  long i = ((long)blockIdx.x*256 + threadIdx.x)*4;
  if (i >= n) return;
  float4 v = *(const float4*)(in + i);
  short4 s4;
  s4.x = f2bf(v.x); s4.y = f2bf(v.y); s4.z = f2bf(v.z); s4.w = f2bf(v.w);
  *(short4*)&o[i] = s4;
}

__global__ __launch_bounds__(256)
void latcopy(const float* __restrict__ latents, float* __restrict__ lat)
{
  int idx = blockIdx.x*256 + threadIdx.x;
  int d = idx % 1152; int j = (idx / 1152) % 64; int b = idx / (1152*64);
  lat[((long)b*128 + j)*1152 + d] = latents[j*1152 + d];
}

template<int OUTF32>
__global__ __launch_bounds__(256)
void ln_k(const float* __restrict__ in, void* __restrict__ outp,
          const float* __restrict__ w, const float* __restrict__ b,
          int grpSel, int grpStride)
{
  const int D = 1152;
  int r = blockIdx.x;
  long ir = (long)(r / grpSel)*grpStride + (r % grpSel);
  const float* x = in + ir*D;
  int tid = threadIdx.x;
  float s1=0.f, s2=0.f;
  float xv[5];
#pragma unroll
  for (int t=0;t<5;t++){
    int i = tid + t*256;
    xv[t] = (i < D) ? x[i] : 0.f;
    s1 += xv[t]; s2 += xv[t]*xv[t];
  }
#pragma unroll
  for (int o=32;o;o>>=1){ s1 += __shfl_xor(s1,o); s2 += __shfl_xor(s2,o); }
  __shared__ float red[8];
  int wid = tid>>6, lane = tid&63;
  if (lane==0){ red[wid]=s1; red[4+wid]=s2; }
  __syncthreads();
  s1 = red[0]+red[1]+red[2]+red[3];
  s2 = red[4]+red[5]+red[6]+red[7];
  float mu = s1 / D;
  float var = s2 / D - mu*mu;
  float rs = rsqrtf(var + 1e-5f);
#pragma unroll
  for (int t=0;t<5;t++){
    int i = tid + t*256;
    if (i >= D) break;
    float v = (xv[t]-mu)*rs;
    if (w) v = v*w[i] + b[i];
    if (OUTF32) ((float*)outp)[(long)r*D + i] = v;
    else        ((short*)outp)[(long)r*D + i] = f2bf(v);
  }
}

// ---------------------------------------------------------------------------

extern "C" void kernel_launch(void* const* d_in, const int* in_sizes, int n_in,
                              void* d_out, int out_size, void* d_ws, size_t ws_size,
                              hipStream_t stream)
{
  const float* x      = (const float*)d_in[0];
  const float* tein   = (const float*)d_in[1];
  const float* lat0   = (const float*)d_in[2];
  const float* txt_w1 = (const float*)d_in[3];
  const float* txt_b1 = (const float*)d_in[4];
  const float* txt_w2 = (const float*)d_in[5];
  const float* txt_b2 = (const float*)d_in[6];
  const float* nm_w   = (const float*)d_in[7];
  const float* nm_b   = (const float*)d_in[8];
  const float* nl_w   = (const float*)d_in[9];
  const float* nl_b   = (const float*)d_in[10];
  const float* Wq     = (const float*)d_in[11];
  const float* Wkv    = (const float*)d_in[12];
  const float* Wo     = (const float*)d_in[13];
  const float* ffln_w = (const float*)d_in[14];
  const float* ffln_b = (const float*)d_in[15];
  const float* ff_w1  = (const float*)d_in[16];
  const float* ff_w2  = (const float*)d_in[17];
  const float* oln_w  = (const float*)d_in[18];
  const float* oln_b  = (const float*)d_in[19];
  float* out = (float*)d_out;
  (void)in_sizes; (void)n_in; (void)out_size; (void)ws_size;

  char* base = (char*)d_ws;
  size_t off = 0;
  auto alloc = [&](size_t bytes)->char*{
    char* r = base + off;
    off += (bytes + 255) & ~(size_t)255;
    return r;
  };
  short* wT    = (short*)alloc(4608ULL*1152*2);   // Wq^T | Wkv^T
  short* wTx   = (short*)alloc(3072ULL*1152*2);   // nm-scaled Wkv^T
  short* wTo   = (short*)alloc(1152ULL*1536*2);   // Wo^T
  short* wTf1  = (short*)alloc(4608ULL*1152*2);   // fw1^T
  short* wTf2  = (short*)alloc(1152ULL*4608*2);   // fw2^T
  float* biasf = (float*)alloc(6*3072*4);
  float* ppart = (float*)alloc(2ULL*4096*1152*4);
  short* xnorm = (short*)alloc(23328ULL*1152*2);
  float* lat   = (float*)alloc(4096ULL*1152*4);
  short* lm    = (short*)alloc(4096ULL*1152*2);
  short* qb    = (short*)alloc(4096ULL*1536*2);
  short* kv    = (short*)alloc(27424ULL*3072*2);
  short* SP    = (short*)alloc(2048ULL*4096*2 + 2048ULL*1152*2);
  short* attn  = (short*)alloc(4096ULL*1536*2);
  short* ffh   = (short*)alloc(4096ULL*4608*2);
  short* txtin = SP;
  short* txth  = SP + 2048ULL*4096;

  // ---- preamble ----
  cvt_bf16x4<<<8192,256,0,stream>>>(tein, txtin, 2048LL*4096);
  convT<<<dim3(36,128),256,0,stream>>>(txt_w1, wT, 4096, 1152, nullptr);
  gemm_t<1,1,0,0><<<dim3(9,16,1),256,0,stream>>>(txtin, wT, txth, txt_b1, nullptr,
      4096,4096,4096,1152, 2048,1152,1152, 1, 0,0,0,0,0,0, 1.f);
  convT<<<dim3(36,36),256,0,stream>>>(txt_w2, wT, 1152, 1152, nullptr);
  gemm_t<0,1,0,1><<<dim3(9,1,32),256,0,stream>>>(txth, wT, lat + 64*1152, txt_b2, nullptr,
      1152,1152,1152,1152, 64,1152,1152, 1, 64L*1152,0, 0,0, 128L*1152,0, 1.f);
  latcopy<<<9216,256,0,stream>>>(lat0, lat);

  ln_k<0><<<23328,256,0,stream>>>(x, xnorm, nullptr, nullptr, 1<<28, 0);
  ln_k<0><<<4096,256,0,stream>>>(lat, lm, nl_w, nl_b, 1<<28, 0);
  biasfold6<<<dim3(12,6),256,0,stream>>>(Wkv, nm_b, biasf);
  // layer-0 weight transposes (subsequent layers come fused from gemm_f2t)
  convT_qkv<<<5184,256,0,stream>>>(Wq, Wkv, nm_w, wT, wTx, wT + 1536*1152);

  for (int L=0; L<6; L++){
    const float* WoL  = Wo    + (size_t)L*1536*1152;
    const float* fw1  = ff_w1 + (size_t)L*1152*4608;
    const float* fw2  = ff_w2 + (size_t)L*4608*1152;
    int Ln = (L+1 < 6) ? (L+1) : 5;   // next-layer weights (L=5: dead recompute)

    // merged q|kv + kvx (wT/wTx prepared by preamble or previous gemm_f2t)
    gemm_qkvx<<<2784,512,0,stream>>>(lm, xnorm, wT, wTx, qb, kv, biasf + L*3072);

    flash_attn<<<512,256,0,stream>>>(qb, kv, attn);

    convT_ffo<<<12096,256,0,stream>>>(WoL, fw1, fw2, wTo, wTf1, wTf2);

    gemm_v2<0,0,1,0,1><<<dim3(32,5,2),512,0,stream>>>(attn, wTo, ppart, nullptr, nullptr,
        768,1536,1536,1152, 4096, 1152, 1152);
    red2_ln<<<4096,256,0,stream>>>(lat, ppart, 4096L*1152, lm,
        ffln_w + L*1152, ffln_b + L*1152);

    gemm_v2<1,0,0,0,0><<<dim3(32,18),512,0,stream>>>(lm, wTf1, ffh, nullptr, nullptr,
        1152,1152,1152,4608, 4096, 4608, 4608);

    // ff2 GEMM + next-layer convT_qkv, co-scheduled in one dispatch
    gemm_f2t<<<5504,512,0,stream>>>(ffh, wTf2, ppart,
        Wq + (size_t)Ln*1152*1536, Wkv + (size_t)Ln*1152*3072, nm_w + Ln*1152,
        wT, wTx, wT + 1536*1152);

    red2_ln<<<4096,256,0,stream>>>(lat, ppart, 4096L*1152, lm,
        (L+1 < 6) ? (nl_w + Ln*1152) : nullptr, nl_b + Ln*1152);
  }

  ln_k<1><<<2048,256,0,stream>>>(lat, out, oln_w, oln_b, 64, 128);
}